// Round 6
// baseline (324.420 us; speedup 1.0000x reference)
//
#include <hip/hip_runtime.h>
#include <hip/hip_fp16.h>
#include <math.h>

typedef __attribute__((ext_vector_type(8))) short short8;
typedef __attribute__((ext_vector_type(4))) float floatx4;
typedef __attribute__((ext_vector_type(2))) float float2v;

__device__ __forceinline__ float bf2f(unsigned short u){
  return __uint_as_float(((unsigned int)u) << 16);
}
__device__ __forceinline__ unsigned short f2bf(float f){
  unsigned int x = __float_as_uint(f);
  unsigned int r = x + 0x7fff + ((x >> 16) & 1);   // RNE
  return (unsigned short)(r >> 16);
}
__device__ __forceinline__ unsigned pack_h2(float a, float b){
  return ((unsigned)__half_as_ushort(__float2half_rn(b)) << 16) |
         (unsigned)__half_as_ushort(__float2half_rn(a));
}
__device__ __forceinline__ float unpack_h(unsigned u, int hi){
  unsigned short us = hi ? (unsigned short)(u >> 16) : (unsigned short)(u & 0xffff);
  return __half2float(__ushort_as_half(us));
}
__device__ __forceinline__ float wsumf(float v){
#pragma unroll
  for (int o = 32; o; o >>= 1) v += __shfl_xor(v, o, 64);
  return v;
}

// ---------------------------------------------------------------- count (sharded banks) + epack
// degp[d] (bank A) / degp[N+d] (bank B): bits[63:40]=count, [39:0]=sum(eattr)*2^24.
__global__ __launch_bounds__(256) void k_count(const int* __restrict__ src,
    const int* __restrict__ dst, const float* __restrict__ eattr,
    unsigned long long* __restrict__ degp, int4* __restrict__ epack,
    int E, int Eh, int N){
  int e = blockIdx.x * 256 + threadIdx.x;
  if (e >= E) return;
  int d = dst[e];
  float ea = eattr[e];
  unsigned long long add = (1ull << 40) |
      (unsigned long long)(ea * 16777216.0f);
  unsigned long long* bank = degp + (e < Eh ? 0 : N);
  unsigned long long old = atomicAdd(&bank[d], add);
  epack[e] = make_int4(src[e], d, __float_as_int(ea), (int)(old >> 40));
}

// ---------------------------------------------------------------- scan (3 phases)
__global__ __launch_bounds__(256) void k_scan1(const unsigned long long* __restrict__ degp,
    int* __restrict__ row_ptr, int* __restrict__ bsum, int n){
  __shared__ int sm[2][256];
  int tid = threadIdx.x, gid = blockIdx.x * 256 + tid;
  int v = 0;
  if (gid < n) v = (int)(degp[gid] >> 40) + (int)(degp[gid + n] >> 40);
  sm[0][tid] = v; __syncthreads();
  int pin = 0;
  for (int off = 1; off < 256; off <<= 1){
    int t = sm[pin][tid];
    if (tid >= off) t += sm[pin][tid - off];
    sm[pin ^ 1][tid] = t; pin ^= 1; __syncthreads();
  }
  int incl = sm[pin][tid];
  if (gid < n) row_ptr[gid] = incl - v;
  if (tid == 255) bsum[blockIdx.x] = incl;
}

__global__ __launch_bounds__(256) void k_scan2(const int* __restrict__ bsum,
    int* __restrict__ bofs, int nb){
  __shared__ int sm[2][256];
  int tid = threadIdx.x;
  int v = (tid < nb) ? bsum[tid] : 0;
  sm[0][tid] = v; __syncthreads();
  int pin = 0;
  for (int off = 1; off < 256; off <<= 1){
    int t = sm[pin][tid];
    if (tid >= off) t += sm[pin][tid - off];
    sm[pin ^ 1][tid] = t; pin ^= 1; __syncthreads();
  }
  bofs[tid] = sm[pin][tid] - v;
}

__global__ __launch_bounds__(256) void k_scan3(int* __restrict__ row_ptr,
    const int* __restrict__ bofs, const unsigned long long* __restrict__ degp,
    float* __restrict__ lattr, int2* __restrict__ nodeinfo, int n, int E){
  int gid = blockIdx.x * 256 + threadIdx.x;
  if (gid >= n) return;
  int rp = row_ptr[gid] + bofs[gid >> 8];
  row_ptr[gid] = rp;
  unsigned long long pA = degp[gid], pB = degp[gid + n];
  int dA = (int)(pA >> 40), dB = (int)(pB >> 40);
  const unsigned long long M40 = (1ull << 40) - 1;
  float d = (float)(dA + dB);
  float s = ((float)(pA & M40) + (float)(pB & M40)) * (1.0f / 16777216.0f);
  lattr[gid] = s / fmaxf(d, 1.0f);
  nodeinfo[gid] = make_int2(rp, dA);
  if (gid == 0) row_ptr[n] = E;
}

// ---------------------------------------------------------------- pack B into MFMA frag layout
__global__ void k_packB(const float* __restrict__ W, unsigned short* __restrict__ Bp,
                        int K, int N){
  int lane = threadIdx.x;
  int nt = blockIdx.x, kc = blockIdx.y, nkc = gridDim.y;
  int col = nt * 16 + (lane & 15);
  int krow = kc * 32 + (lane >> 4) * 8;
  unsigned short tmp[8];
#pragma unroll
  for (int j = 0; j < 8; j++) tmp[j] = f2bf(W[(size_t)(krow + j) * N + col]);
  unsigned short* dstp = Bp + (((size_t)nt * nkc + kc) * 64 + lane) * 8;
  *(ushort4*)(dstp)     = make_ushort4(tmp[0], tmp[1], tmp[2], tmp[3]);
  *(ushort4*)(dstp + 4) = make_ushort4(tmp[4], tmp[5], tmp[6], tmp[7]);
}

// ---------------------------------------------------------------- edge coeffs
__global__ void k_ce(const float* __restrict__ We1, const float* __restrict__ ae1,
    const float* __restrict__ We2, const float* __restrict__ ae2,
    float* __restrict__ ce){
  int lane = threadIdx.x;
  float p0 = We1[lane]       * ae1[lane];
  float p1 = We1[64 + lane]  * ae1[64 + lane];
  float p2 = We1[128 + lane] * ae1[128 + lane];
  float p3 = We1[192 + lane] * ae1[192 + lane];
  float p4 = We2[lane]       * ae2[lane];
  p0 = wsumf(p0); p1 = wsumf(p1); p2 = wsumf(p2); p3 = wsumf(p3); p4 = wsumf(p4);
  if (lane == 0){ ce[0] = p0; ce[1] = p1; ce[2] = p2; ce[3] = p3; ce[4] = p4; }
}

// ---------------------------------------------------------------- GEMM1 (fp32 A) + attscore1 epilogue
// N=256,K=128. Scores: per row r, per head h: asrc[r][h]=sum_{c in head} h1pre[r][c]*as1[c].
__global__ __launch_bounds__(256) void k_gemm1_att(const float* __restrict__ A,
    const unsigned short* __restrict__ Bp, unsigned short* __restrict__ C,
    const float* __restrict__ as_, const float* __restrict__ ad_,
    float* __restrict__ outS, float* __restrict__ outD, int M){
  constexpr int K = 128, N = 256, NKC = 4, NNT = 16;
  __shared__ unsigned short Bs[N * K];
  {
    const uint4* srcp = (const uint4*)Bp;
    uint4* dstp = (uint4*)Bs;
    const int total = (N * K * 2) / 16;
    for (int i = threadIdx.x; i < total; i += 256) dstp[i] = srcp[i];
  }
  __syncthreads();
  int wave = threadIdx.x >> 6, lane = threadIdx.x & 63;
  int quad = lane >> 4, col = lane & 15;
  int r0 = (blockIdx.x * 4 + wave) * 16;
  int rowc = min(r0 + col, M - 1);
  short8 af[NKC];
#pragma unroll
  for (int kc = 0; kc < NKC; kc++){
    float4 a0 = *(const float4*)(A + (size_t)rowc * K + kc * 32 + quad * 8);
    float4 a1 = *(const float4*)(A + (size_t)rowc * K + kc * 32 + quad * 8 + 4);
    short8 t;
    t[0] = (short)f2bf(a0.x); t[1] = (short)f2bf(a0.y);
    t[2] = (short)f2bf(a0.z); t[3] = (short)f2bf(a0.w);
    t[4] = (short)f2bf(a1.x); t[5] = (short)f2bf(a1.y);
    t[6] = (short)f2bf(a1.z); t[7] = (short)f2bf(a1.w);
    af[kc] = t;
  }
  floatx4 acc[NNT];
#pragma unroll
  for (int nt = 0; nt < NNT; nt++) acc[nt] = (floatx4){0.f, 0.f, 0.f, 0.f};
#pragma unroll
  for (int kc = 0; kc < NKC; kc++){
#pragma unroll
    for (int nt = 0; nt < NNT; nt++){
      short8 bfv = *(const short8*)(&Bs[((nt * NKC + kc) * 64 + lane) * 8]);
      acc[nt] = __builtin_amdgcn_mfma_f32_16x16x32_bf16(af[kc], bfv, acc[nt], 0, 0, 0);
    }
  }
  // store C (bf16)
#pragma unroll
  for (int nt = 0; nt < NNT; nt++){
#pragma unroll
    for (int i = 0; i < 4; i++){
      int r = r0 + quad * 4 + i;
      if (r < M) C[(size_t)r * N + nt * 16 + col] = f2bf(acc[nt][i]);
    }
  }
  // attscore epilogue
  float asv[NNT], adv[NNT];
#pragma unroll
  for (int nt = 0; nt < NNT; nt++){
    asv[nt] = as_[nt * 16 + col];
    adv[nt] = ad_[nt * 16 + col];
  }
#pragma unroll
  for (int i = 0; i < 4; i++){
    float sh[4] = {0.f,0.f,0.f,0.f}, dh[4] = {0.f,0.f,0.f,0.f};
#pragma unroll
    for (int nt = 0; nt < NNT; nt++){
      int h = nt >> 2;
      sh[h] += acc[nt][i] * asv[nt];
      dh[h] += acc[nt][i] * adv[nt];
    }
#pragma unroll
    for (int o = 1; o < 16; o <<= 1){
#pragma unroll
      for (int h = 0; h < 4; h++){
        sh[h] += __shfl_xor(sh[h], o, 64);
        dh[h] += __shfl_xor(dh[h], o, 64);
      }
    }
    int r = r0 + quad * 4 + i;
    if (col == 0 && r < M){
      *(float4*)(outS + (size_t)r * 4) = make_float4(sh[0], sh[1], sh[2], sh[3]);
      *(float4*)(outD + (size_t)r * 4) = make_float4(dh[0], dh[1], dh[2], dh[3]);
    }
  }
}

// ---------------------------------------------------------------- GEMM2 (bf16 A) + attscore2 epilogue
__global__ __launch_bounds__(256) void k_gemm2_att(const unsigned short* __restrict__ A,
    const unsigned short* __restrict__ Bp, unsigned short* __restrict__ C,
    const float* __restrict__ as_, const float* __restrict__ ad_,
    float* __restrict__ outS, float* __restrict__ outD, int M){
  constexpr int K = 256, N = 64, NKC = 8, NNT = 4;
  __shared__ unsigned short Bs[N * K];
  {
    const uint4* srcp = (const uint4*)Bp;
    uint4* dstp = (uint4*)Bs;
    const int total = (N * K * 2) / 16;
    for (int i = threadIdx.x; i < total; i += 256) dstp[i] = srcp[i];
  }
  __syncthreads();
  int wave = threadIdx.x >> 6, lane = threadIdx.x & 63;
  int quad = lane >> 4, col = lane & 15;
  int r0 = (blockIdx.x * 4 + wave) * 16;
  int rowc = min(r0 + col, M - 1);
  short8 af[NKC];
#pragma unroll
  for (int kc = 0; kc < NKC; kc++)
    af[kc] = *(const short8*)(A + (size_t)rowc * K + kc * 32 + quad * 8);
  floatx4 acc[NNT];
#pragma unroll
  for (int nt = 0; nt < NNT; nt++) acc[nt] = (floatx4){0.f, 0.f, 0.f, 0.f};
#pragma unroll
  for (int kc = 0; kc < NKC; kc++){
#pragma unroll
    for (int nt = 0; nt < NNT; nt++){
      short8 bfv = *(const short8*)(&Bs[((nt * NKC + kc) * 64 + lane) * 8]);
      acc[nt] = __builtin_amdgcn_mfma_f32_16x16x32_bf16(af[kc], bfv, acc[nt], 0, 0, 0);
    }
  }
#pragma unroll
  for (int nt = 0; nt < NNT; nt++){
#pragma unroll
    for (int i = 0; i < 4; i++){
      int r = r0 + quad * 4 + i;
      if (r < M) C[(size_t)r * N + nt * 16 + col] = f2bf(acc[nt][i]);
    }
  }
  float asv[NNT], adv[NNT];
#pragma unroll
  for (int nt = 0; nt < NNT; nt++){
    asv[nt] = as_[nt * 16 + col];
    adv[nt] = ad_[nt * 16 + col];
  }
#pragma unroll
  for (int i = 0; i < 4; i++){
    float s = 0.f, d = 0.f;
#pragma unroll
    for (int nt = 0; nt < NNT; nt++){
      s += acc[nt][i] * asv[nt];
      d += acc[nt][i] * adv[nt];
    }
#pragma unroll
    for (int o = 1; o < 16; o <<= 1){
      s += __shfl_xor(s, o, 64);
      d += __shfl_xor(d, o, 64);
    }
    int r = r0 + quad * 4 + i;
    if (col == 0 && r < M){ outS[r] = s; outD[r] = d; }
  }
}

// ---------------------------------------------------------------- edge weight prepass L1 (fused scatter)
__global__ __launch_bounds__(256) void k_wpre1(const int4* __restrict__ epack,
    const int2* __restrict__ nodeinfo,
    const float* __restrict__ a_src, const float* __restrict__ a_dst,
    const float* __restrict__ ce, int4* __restrict__ wcsr, int E, int Eh){
  int e = blockIdx.x * 256 + threadIdx.x;
  if (e >= E) return;
  int4 c = epack[e];               // {src, dst, ea, rank}
  float ea = __int_as_float(c.z);
  int2 ni = nodeinfo[c.y];         // {rowptr, degA}
  int pos = ni.x + c.w + (e < Eh ? 0 : ni.y);
  float4 as4 = *(const float4*)(a_src + (size_t)c.x * 4);
  float4 ad4 = *(const float4*)(a_dst + (size_t)c.y * 4);
  float4 ce4 = *(const float4*)ce;
  float a0 = as4.x + ad4.x + ea * ce4.x; a0 = a0 > 0.f ? a0 : 0.2f * a0;
  float a1 = as4.y + ad4.y + ea * ce4.y; a1 = a1 > 0.f ? a1 : 0.2f * a1;
  float a2 = as4.z + ad4.z + ea * ce4.z; a2 = a2 > 0.f ? a2 : 0.2f * a2;
  float a3 = as4.w + ad4.w + ea * ce4.w; a3 = a3 > 0.f ? a3 : 0.2f * a3;
  unsigned u01 = pack_h2(__expf(a0), __expf(a1));
  unsigned u23 = pack_h2(__expf(a2), __expf(a3));
  wcsr[pos] = make_int4(c.x, (int)u01, (int)u23, 0);
}

// ---------------------------------------------------------------- edge weight prepass L2 (fused scatter)
__global__ __launch_bounds__(256) void k_wpre2(const int4* __restrict__ epack,
    const int2* __restrict__ nodeinfo,
    const float* __restrict__ a_src, const float* __restrict__ a_dst,
    const float* __restrict__ ce, int2* __restrict__ wcsr2, int E, int Eh){
  int e = blockIdx.x * 256 + threadIdx.x;
  if (e >= E) return;
  int4 c = epack[e];
  float ea = __int_as_float(c.z);
  int2 ni = nodeinfo[c.y];
  int pos = ni.x + c.w + (e < Eh ? 0 : ni.y);
  float a = a_src[c.x] + a_dst[c.y] + ea * ce[4];
  a = a > 0.f ? a : 0.2f * a;
  wcsr2[pos] = make_int2(c.x, __float_as_int(__expf(a)));
}

// ---------------------------------------------------------------- GAT layer 1
// Quarter-wave (16 lanes) per edge; lane covers 16 channels; packed f32 math.
__global__ __launch_bounds__(256) void k_gat1(
    const int* __restrict__ row_ptr, const int4* __restrict__ wcsr,
    const float* __restrict__ lattr,
    const float* __restrict__ a_src, const float* __restrict__ a_dst,
    const float* __restrict__ ce, const unsigned short* __restrict__ hpre,
    const float* __restrict__ bias, unsigned short* __restrict__ hout, int n){
  int node = blockIdx.x * 4 + (threadIdx.x >> 6);
  if (node >= n) return;
  int lane = threadIdx.x & 63;
  int q = lane >> 4, lsub = lane & 15, hq = lsub >> 2;
  int start = row_ptr[node], deg = row_ptr[node + 1] - start;
  int total = deg + 1;
  float4 as4 = *(const float4*)(a_src + (size_t)node * 4);
  float4 ad4 = *(const float4*)(a_dst + (size_t)node * 4);
  float4 ce4 = *(const float4*)ce;
  float la = lattr[node];
  float asvh = hq == 0 ? as4.x : hq == 1 ? as4.y : hq == 2 ? as4.z : as4.w;
  float advh = hq == 0 ? ad4.x : hq == 1 ? ad4.y : hq == 2 ? ad4.z : ad4.w;
  float ceh  = hq == 0 ? ce4.x : hq == 1 ? ce4.y : hq == 2 ? ce4.z : ce4.w;
  float aself = asvh + advh + la * ceh;
  aself = aself > 0.f ? aself : 0.2f * aself;
  float wself = __expf(aself);
  float2v acc2[8];
#pragma unroll
  for (int k = 0; k < 8; k++) acc2[k] = (float2v){0.f, 0.f};
  float dn = 0.f;
  for (int e = q; e < total; e += 4){
    int s; float wv;
    if (e < deg){
      int4 we = wcsr[start + e];
      s = we.x;
      unsigned wb = (hq & 2) ? (unsigned)we.z : (unsigned)we.y;
      wv = unpack_h(wb, hq & 1);
    } else { s = node; wv = wself; }
    dn += wv;
    const uint4* hp = (const uint4*)(hpre + (size_t)s * 256 + lsub * 16);
    uint4 u0 = hp[0], u1 = hp[1];
    float2v w2 = (float2v){wv, wv};
    unsigned uu[8] = {u0.x, u0.y, u0.z, u0.w, u1.x, u1.y, u1.z, u1.w};
#pragma unroll
    for (int j = 0; j < 8; j++){
      float2v hv;
      hv.x = __uint_as_float(uu[j] << 16);
      hv.y = __uint_as_float(uu[j] & 0xffff0000u);
      acc2[j] += w2 * hv;
    }
  }
  dn += __shfl_xor(dn, 16, 64);
  dn += __shfl_xor(dn, 32, 64);
#pragma unroll
  for (int k = 0; k < 8; k++){
    acc2[k].x += __shfl_xor(acc2[k].x, 16, 64);
    acc2[k].x += __shfl_xor(acc2[k].x, 32, 64);
    acc2[k].y += __shfl_xor(acc2[k].y, 16, 64);
    acc2[k].y += __shfl_xor(acc2[k].y, 32, 64);
  }
  if (q == 0){
    float inv = 1.f / dn;
    float bb[16];
#pragma unroll
    for (int j = 0; j < 4; j++){
      float4 b4 = *(const float4*)(bias + lsub * 16 + j * 4);
      bb[j * 4 + 0] = b4.x; bb[j * 4 + 1] = b4.y;
      bb[j * 4 + 2] = b4.z; bb[j * 4 + 3] = b4.w;
    }
    unsigned short o[16];
#pragma unroll
    for (int k = 0; k < 16; k++){
      float av = (k & 1) ? acc2[k >> 1].y : acc2[k >> 1].x;
      float v = av * inv + bb[k];
      v = v > 0.f ? v : (__expf(v) - 1.f);
      o[k] = f2bf(v);
    }
    unsigned short* op = hout + (size_t)node * 256 + lsub * 16;
    *(uint4*)(op)     = *(uint4*)(o);
    *(uint4*)(op + 8) = *(uint4*)(o + 8);
  }
}

// ---------------------------------------------------------------- GAT layer 2 + pair projection
__global__ __launch_bounds__(256) void k_gat2(
    const int* __restrict__ row_ptr, const int2* __restrict__ wcsr2,
    const float* __restrict__ lattr,
    const float* __restrict__ a_src, const float* __restrict__ a_dst,
    const float* __restrict__ ce, const unsigned short* __restrict__ hpre,
    const float* __restrict__ bias, const float* __restrict__ Wlin,
    float* __restrict__ s1v, float* __restrict__ s2v, int n){
  int node = blockIdx.x * 4 + (threadIdx.x >> 6);
  if (node >= n) return;
  int lane = threadIdx.x & 63;
  int slot = lane >> 3, lsub = lane & 7;
  int start = row_ptr[node], deg = row_ptr[node + 1] - start;
  int total = deg + 1;
  float aself = a_src[node] + a_dst[node] + lattr[node] * ce[4];
  aself = aself > 0.f ? aself : 0.2f * aself;
  float wself = __expf(aself);
  float2v acc2[4];
#pragma unroll
  for (int k = 0; k < 4; k++) acc2[k] = (float2v){0.f, 0.f};
  float dn = 0.f;
  for (int e = slot; e < total; e += 8){
    int s; float wv;
    if (e < deg){ int2 se = wcsr2[start + e]; s = se.x; wv = __int_as_float(se.y); }
    else        { s = node; wv = wself; }
    dn += wv;
    uint4 u = *(const uint4*)(hpre + (size_t)s * 64 + lsub * 8);
    float2v w2 = (float2v){wv, wv};
    unsigned uu[4] = {u.x, u.y, u.z, u.w};
#pragma unroll
    for (int j = 0; j < 4; j++){
      float2v hv;
      hv.x = __uint_as_float(uu[j] << 16);
      hv.y = __uint_as_float(uu[j] & 0xffff0000u);
      acc2[j] += w2 * hv;
    }
  }
#pragma unroll
  for (int o = 8; o < 64; o <<= 1){
    dn += __shfl_xor(dn, o, 64);
#pragma unroll
    for (int k = 0; k < 4; k++){
      acc2[k].x += __shfl_xor(acc2[k].x, o, 64);
      acc2[k].y += __shfl_xor(acc2[k].y, o, 64);
    }
  }
  float inv = 1.f / dn;
  float t1 = 0.f, t2 = 0.f;
#pragma unroll
  for (int k = 0; k < 8; k++){
    float av = (k & 1) ? acc2[k >> 1].y : acc2[k >> 1].x;
    float v = av * inv + bias[lsub * 8 + k];
    t1 += v * Wlin[lsub * 8 + k];
    t2 += v * Wlin[64 + lsub * 8 + k];
  }
#pragma unroll
  for (int o = 1; o < 8; o <<= 1){
    t1 += __shfl_xor(t1, o, 64);
    t2 += __shfl_xor(t2, o, 64);
  }
  if (lane == 0){ s1v[node] = t1; s2v[node] = t2; }
}

// ---------------------------------------------------------------- pair head
__global__ __launch_bounds__(256) void k_pairs(const int* __restrict__ pairs,
    const float* __restrict__ s1v, const float* __restrict__ s2v,
    const float* __restrict__ blin, float* __restrict__ out, int P){
  int p = blockIdx.x * 256 + threadIdx.x;
  if (p >= P) return;
  int i = pairs[2 * p], j = pairs[2 * p + 1];
  float x = s1v[i] + s2v[j] + blin[0];
  out[p] = 1.f / (1.f + __expf(-x));
}

// ---------------------------------------------------------------- launch
extern "C" void kernel_launch(void* const* d_in, const int* in_sizes, int n_in,
                              void* d_out, int out_size, void* d_ws, size_t ws_size,
                              hipStream_t stream) {
  const float* x     = (const float*)d_in[0];
  const int*   esrc  = (const int*)  d_in[1];
  const int*   edst  = (const int*)  d_in[2];
  const float* eattr = (const float*)d_in[3];
  const int*   pairs = (const int*)  d_in[4];
  const float* W1    = (const float*)d_in[5];
  const float* We1   = (const float*)d_in[6];
  const float* as1   = (const float*)d_in[7];
  const float* ad1   = (const float*)d_in[8];
  const float* ae1   = (const float*)d_in[9];
  const float* b1    = (const float*)d_in[10];
  const float* W2    = (const float*)d_in[11];
  const float* We2   = (const float*)d_in[12];
  const float* as2   = (const float*)d_in[13];
  const float* ad2   = (const float*)d_in[14];
  const float* ae2   = (const float*)d_in[15];
  const float* b2    = (const float*)d_in[16];
  const float* Wlin  = (const float*)d_in[17];
  const float* blin  = (const float*)d_in[18];
  float* out = (float*)d_out;

  const int N = in_sizes[0] / 128;
  const int E = in_sizes[1];
  const int Eh = E / 2;
  const int P = in_sizes[4] / 2;

  char* w = (char*)d_ws;
  size_t off = 0;
  auto alloc = [&](size_t bytes) -> size_t {
    size_t r = off; off = (off + bytes + 255) & ~(size_t)255; return r;
  };
  size_t o_degp   = alloc((size_t)N * 16);   // 2 banks of u64
  size_t zero_end = off;
  size_t o_epack  = alloc((size_t)E * 16);
  size_t o_rowptr = alloc((size_t)(N + 1) * 4);
  size_t o_bsum   = alloc(1024);
  size_t o_bofs   = alloc(1024);
  size_t o_lattr  = alloc((size_t)N * 4);
  size_t o_ninfo  = alloc((size_t)N * 8);
  size_t o_wcsr1  = alloc((size_t)E * 16);
  size_t o_wcsr2  = alloc((size_t)E * 8);
  size_t o_asrc1  = alloc((size_t)N * 16);
  size_t o_adst1  = alloc((size_t)N * 16);
  size_t o_asrc2  = alloc((size_t)N * 4);
  size_t o_adst2  = alloc((size_t)N * 4);
  size_t o_ce     = alloc(32);
  size_t o_s1     = alloc((size_t)N * 4);
  size_t o_s2     = alloc((size_t)N * 4);
  size_t o_W1p    = alloc(128 * 256 * 2);
  size_t o_W2p    = alloc(256 * 64 * 2);
  size_t o_h1preb = alloc((size_t)N * 256 * 2);
  size_t o_h1b    = alloc((size_t)N * 256 * 2);
  size_t o_h2preb = alloc((size_t)N * 64 * 2);
  (void)ws_size;

  unsigned long long* degp = (unsigned long long*)(w + o_degp);
  int4*  epack  = (int4*) (w + o_epack);
  int*   rowptr = (int*)  (w + o_rowptr);
  int*   bsum   = (int*)  (w + o_bsum);
  int*   bofs   = (int*)  (w + o_bofs);
  float* lattr  = (float*)(w + o_lattr);
  int2*  ninfo  = (int2*) (w + o_ninfo);
  int4*  wcsr1  = (int4*) (w + o_wcsr1);
  int2*  wcsr2  = (int2*) (w + o_wcsr2);
  float* asrc1  = (float*)(w + o_asrc1);
  float* adst1  = (float*)(w + o_adst1);
  float* asrc2  = (float*)(w + o_asrc2);
  float* adst2  = (float*)(w + o_adst2);
  float* ce     = (float*)(w + o_ce);
  float* s1v    = (float*)(w + o_s1);
  float* s2v    = (float*)(w + o_s2);
  unsigned short* W1p    = (unsigned short*)(w + o_W1p);
  unsigned short* W2p    = (unsigned short*)(w + o_W2p);
  unsigned short* h1preb = (unsigned short*)(w + o_h1preb);
  unsigned short* h1b    = (unsigned short*)(w + o_h1b);
  unsigned short* h2preb = (unsigned short*)(w + o_h2preb);

  hipMemsetAsync(w, 0, zero_end, stream);

  int ebl = (E + 255) / 256;
  int nbl = (N + 255) / 256;
  int wbl = (N + 3) / 4;

  // CSR metadata (no materialized csr: wpre kernels scatter directly)
  k_count<<<ebl, 256, 0, stream>>>(esrc, edst, eattr, degp, epack, E, Eh, N);
  k_scan1<<<nbl, 256, 0, stream>>>(degp, rowptr, bsum, N);
  k_scan2<<<1, 256, 0, stream>>>(bsum, bofs, nbl);
  k_scan3<<<nbl, 256, 0, stream>>>(rowptr, bofs, degp, lattr, ninfo, N, E);

  // weight packing + edge coeffs
  k_packB<<<dim3(16, 4), 64, 0, stream>>>(W1, W1p, 128, 256);
  k_packB<<<dim3(4, 8), 64, 0, stream>>>(W2, W2p, 256, 64);
  k_ce<<<1, 64, 0, stream>>>(We1, ae1, We2, ae2, ce);

  // layer 1
  k_gemm1_att<<<(N + 63) / 64, 256, 0, stream>>>(x, W1p, h1preb, as1, ad1,
                                                 asrc1, adst1, N);
  k_wpre1<<<ebl, 256, 0, stream>>>(epack, ninfo, asrc1, adst1, ce, wcsr1, E, Eh);
  k_gat1<<<wbl, 256, 0, stream>>>(rowptr, wcsr1, lattr, asrc1, adst1, ce,
                                  h1preb, b1, h1b, N);
  // layer 2
  k_gemm2_att<<<(N + 63) / 64, 256, 0, stream>>>(h1b, W2p, h2preb, as2, ad2,
                                                 asrc2, adst2, N);
  k_wpre2<<<ebl, 256, 0, stream>>>(epack, ninfo, asrc2, adst2, ce, wcsr2, E, Eh);
  k_gat2<<<wbl, 256, 0, stream>>>(rowptr, wcsr2, lattr, asrc2, adst2, ce,
                                  h2preb, b2, Wlin, s1v, s2v, N);
  // pair head
  k_pairs<<<(P + 255) / 256, 256, 0, stream>>>(pairs, s1v, s2v, blin, out, P);
}

// Round 7
// 309.107 us; speedup vs baseline: 1.0495x; 1.0495x over previous
//
#include <hip/hip_runtime.h>
#include <hip/hip_fp16.h>
#include <math.h>

typedef __attribute__((ext_vector_type(8))) short short8;
typedef __attribute__((ext_vector_type(4))) float floatx4;
typedef __attribute__((ext_vector_type(2))) float float2v;

__device__ __forceinline__ unsigned short f2bf(float f){
  unsigned int x = __float_as_uint(f);
  unsigned int r = x + 0x7fff + ((x >> 16) & 1);   // RNE
  return (unsigned short)(r >> 16);
}
__device__ __forceinline__ unsigned pack_h2(float a, float b){
  return ((unsigned)__half_as_ushort(__float2half_rn(b)) << 16) |
         (unsigned)__half_as_ushort(__float2half_rn(a));
}
__device__ __forceinline__ float unpack_h(unsigned u, int hi){
  unsigned short us = hi ? (unsigned short)(u >> 16) : (unsigned short)(u & 0xffff);
  return __half2float(__ushort_as_half(us));
}
__device__ __forceinline__ unsigned char f2fp8(float v){
  int pk = __builtin_amdgcn_cvt_pk_fp8_f32(v, 0.f, 0, false);
  return (unsigned char)(pk & 0xff);
}
__device__ __forceinline__ float wsumf(float v){
#pragma unroll
  for (int o = 32; o; o >>= 1) v += __shfl_xor(v, o, 64);
  return v;
}

// ---------------------------------------------------------------- count: 4 sharded banks, 1 u64 atomic/edge
// degp[b*N+d]: bits[63:40]=count, [39:0]=sum(eattr)*2^24. epack={src,dst,ea,rank-in-bank}
__global__ __launch_bounds__(256) void k_count(const int* __restrict__ src,
    const int* __restrict__ dst, const float* __restrict__ eattr,
    unsigned long long* __restrict__ degp, int4* __restrict__ epack,
    int E, int Eq, int N){
  int e = blockIdx.x * 256 + threadIdx.x;
  if (e >= E) return;
  int d = dst[e];
  float ea = eattr[e];
  int b = (e >= Eq) + (e >= 2 * Eq) + (e >= 3 * Eq);
  unsigned long long add = (1ull << 40) |
      (unsigned long long)(ea * 16777216.0f);
  unsigned long long old = atomicAdd(&degp[(size_t)b * N + d], add);
  epack[e] = make_int4(src[e], d, __float_as_int(ea), (int)(old >> 40));
}

// ---------------------------------------------------------------- scans
__global__ __launch_bounds__(256) void k_scan1(const unsigned long long* __restrict__ degp,
    int* __restrict__ row_ptr, int* __restrict__ bsum, int n){
  __shared__ int sm[2][256];
  int tid = threadIdx.x, gid = blockIdx.x * 256 + tid;
  int v = 0;
  if (gid < n){
#pragma unroll
    for (int b = 0; b < 4; b++) v += (int)(degp[(size_t)b * n + gid] >> 40);
  }
  sm[0][tid] = v; __syncthreads();
  int pin = 0;
  for (int off = 1; off < 256; off <<= 1){
    int t = sm[pin][tid];
    if (tid >= off) t += sm[pin][tid - off];
    sm[pin ^ 1][tid] = t; pin ^= 1; __syncthreads();
  }
  int incl = sm[pin][tid];
  if (gid < n) row_ptr[gid] = incl - v;
  if (tid == 255) bsum[blockIdx.x] = incl;
}

__global__ __launch_bounds__(256) void k_scan2(const int* __restrict__ bsum,
    int* __restrict__ bofs, int nb){
  __shared__ int sm[2][256];
  int tid = threadIdx.x;
  int v = (tid < nb) ? bsum[tid] : 0;
  sm[0][tid] = v; __syncthreads();
  int pin = 0;
  for (int off = 1; off < 256; off <<= 1){
    int t = sm[pin][tid];
    if (tid >= off) t += sm[pin][tid - off];
    sm[pin ^ 1][tid] = t; pin ^= 1; __syncthreads();
  }
  bofs[tid] = sm[pin][tid] - v;
}

__global__ __launch_bounds__(256) void k_scan3(int* __restrict__ row_ptr,
    const int* __restrict__ bofs, const unsigned long long* __restrict__ degp,
    float* __restrict__ lattr, int4* __restrict__ nodeinfo, int n, int E){
  int gid = blockIdx.x * 256 + threadIdx.x;
  if (gid >= n) return;
  int rp = row_ptr[gid] + bofs[gid >> 8];
  row_ptr[gid] = rp;
  const unsigned long long M40 = (1ull << 40) - 1;
  unsigned long long p0 = degp[gid];
  unsigned long long p1 = degp[(size_t)n + gid];
  unsigned long long p2 = degp[(size_t)2 * n + gid];
  unsigned long long p3 = degp[(size_t)3 * n + gid];
  int d0 = (int)(p0 >> 40), d1 = (int)(p1 >> 40), d2 = (int)(p2 >> 40), d3 = (int)(p3 >> 40);
  float dtot = (float)(d0 + d1 + d2 + d3);
  float s = ((float)(p0 & M40) + (float)(p1 & M40) + (float)(p2 & M40) + (float)(p3 & M40))
            * (1.0f / 16777216.0f);
  lattr[gid] = s / fmaxf(dtot, 1.0f);
  nodeinfo[gid] = make_int4(rp, d0, d0 + d1, d0 + d1 + d2);
  if (gid == 0) row_ptr[n] = E;
}

// ---------------------------------------------------------------- prep: pack B1 (17 tiles), B2 (5 tiles), ce
// Score tiles: B1 tile16 col h = W1@as1[h], col 4+h = W1@ad1[h]; B2 tile4 col0 = W2@as2, col1 = W2@ad2.
__global__ void k_prep(const float* __restrict__ W1, const float* __restrict__ as1,
    const float* __restrict__ ad1, const float* __restrict__ W2,
    const float* __restrict__ as2, const float* __restrict__ ad2,
    const float* __restrict__ We1, const float* __restrict__ ae1,
    const float* __restrict__ We2, const float* __restrict__ ae2,
    unsigned short* __restrict__ W1p, unsigned short* __restrict__ W2p,
    float* __restrict__ ce){
  int b = blockIdx.x, lane = threadIdx.x;
  if (b < 68){                                   // gemm1 tiles: nt 0..16, kc 0..3
    int nt = b >> 2, kc = b & 3;
    int col = lane & 15, krow = kc * 32 + (lane >> 4) * 8;
    unsigned short tmp[8];
    if (nt < 16){
#pragma unroll
      for (int j = 0; j < 8; j++) tmp[j] = f2bf(W1[(size_t)(krow + j) * 256 + nt * 16 + col]);
    } else {
#pragma unroll
      for (int j = 0; j < 8; j++){
        float v = 0.f;
        if (col < 8){
          const float* av = (col < 4) ? as1 : ad1;
          int h = col & 3;
          for (int c = 0; c < 64; c++)
            v += W1[(size_t)(krow + j) * 256 + h * 64 + c] * av[h * 64 + c];
        }
        tmp[j] = f2bf(v);
      }
    }
    unsigned short* dstp = W1p + (((size_t)nt * 4 + kc) * 64 + lane) * 8;
    *(ushort4*)(dstp)     = make_ushort4(tmp[0], tmp[1], tmp[2], tmp[3]);
    *(ushort4*)(dstp + 4) = make_ushort4(tmp[4], tmp[5], tmp[6], tmp[7]);
  } else if (b < 108){                           // gemm2 tiles: nt 0..4, kc 0..7
    int bb = b - 68;
    int nt = bb >> 3, kc = bb & 7;
    int col = lane & 15, krow = kc * 32 + (lane >> 4) * 8;
    unsigned short tmp[8];
    if (nt < 4){
#pragma unroll
      for (int j = 0; j < 8; j++) tmp[j] = f2bf(W2[(size_t)(krow + j) * 64 + nt * 16 + col]);
    } else {
#pragma unroll
      for (int j = 0; j < 8; j++){
        float v = 0.f;
        if (col < 2){
          const float* av = (col == 0) ? as2 : ad2;
          for (int c = 0; c < 64; c++)
            v += W2[(size_t)(krow + j) * 64 + c] * av[c];
        }
        tmp[j] = f2bf(v);
      }
    }
    unsigned short* dstp = W2p + (((size_t)nt * 8 + kc) * 64 + lane) * 8;
    *(ushort4*)(dstp)     = make_ushort4(tmp[0], tmp[1], tmp[2], tmp[3]);
    *(ushort4*)(dstp + 4) = make_ushort4(tmp[4], tmp[5], tmp[6], tmp[7]);
  } else {                                       // ce
    float p0 = We1[lane]       * ae1[lane];
    float p1 = We1[64 + lane]  * ae1[64 + lane];
    float p2 = We1[128 + lane] * ae1[128 + lane];
    float p3 = We1[192 + lane] * ae1[192 + lane];
    float p4 = We2[lane]       * ae2[lane];
    p0 = wsumf(p0); p1 = wsumf(p1); p2 = wsumf(p2); p3 = wsumf(p3); p4 = wsumf(p4);
    if (lane == 0){ ce[0] = p0; ce[1] = p1; ce[2] = p2; ce[3] = p3; ce[4] = p4; }
  }
}

// ---------------------------------------------------------------- GEMM1: fp32 A, 16 LDS tiles + reg score tile
// Outputs: fp8 table h1f8[N][256], scores asrc1/adst1[N][4] (no shuffles).
__global__ __launch_bounds__(256) void k_gemm1_att(const float* __restrict__ A,
    const unsigned short* __restrict__ Bp, unsigned char* __restrict__ h1f8,
    float* __restrict__ asrc, float* __restrict__ adst, int M){
  constexpr int K = 128, NKC = 4;
  __shared__ unsigned short Bs[256 * K];
  {
    const uint4* srcp = (const uint4*)Bp;
    uint4* dstp = (uint4*)Bs;
    for (int i = threadIdx.x; i < 4096; i += 256) dstp[i] = srcp[i];
  }
  __syncthreads();
  int wave = threadIdx.x >> 6, lane = threadIdx.x & 63;
  int quad = lane >> 4, col = lane & 15;
  int r0 = (blockIdx.x * 4 + wave) * 16;
  int rowc = min(r0 + col, M - 1);
  short8 af[NKC], sf[NKC];
#pragma unroll
  for (int kc = 0; kc < NKC; kc++){
    float4 a0 = *(const float4*)(A + (size_t)rowc * K + kc * 32 + quad * 8);
    float4 a1 = *(const float4*)(A + (size_t)rowc * K + kc * 32 + quad * 8 + 4);
    short8 t;
    t[0] = (short)f2bf(a0.x); t[1] = (short)f2bf(a0.y);
    t[2] = (short)f2bf(a0.z); t[3] = (short)f2bf(a0.w);
    t[4] = (short)f2bf(a1.x); t[5] = (short)f2bf(a1.y);
    t[6] = (short)f2bf(a1.z); t[7] = (short)f2bf(a1.w);
    af[kc] = t;
    sf[kc] = *(const short8*)(Bp + (((size_t)16 * 4 + kc) * 64 + lane) * 8);
  }
  floatx4 acc[17];
#pragma unroll
  for (int nt = 0; nt < 17; nt++) acc[nt] = (floatx4){0.f, 0.f, 0.f, 0.f};
#pragma unroll
  for (int kc = 0; kc < NKC; kc++){
#pragma unroll
    for (int nt = 0; nt < 16; nt++){
      short8 bfv = *(const short8*)(&Bs[((nt * NKC + kc) * 64 + lane) * 8]);
      acc[nt] = __builtin_amdgcn_mfma_f32_16x16x32_bf16(af[kc], bfv, acc[nt], 0, 0, 0);
    }
    acc[16] = __builtin_amdgcn_mfma_f32_16x16x32_bf16(af[kc], sf[kc], acc[16], 0, 0, 0);
  }
#pragma unroll
  for (int nt = 0; nt < 16; nt++){
#pragma unroll
    for (int i = 0; i < 4; i++){
      int r = r0 + quad * 4 + i;
      if (r < M) h1f8[(size_t)r * 256 + nt * 16 + col] = f2fp8(acc[nt][i]);
    }
  }
#pragma unroll
  for (int i = 0; i < 4; i++){
    int r = r0 + quad * 4 + i;
    if (r < M){
      float v = acc[16][i];
      if (col < 4)      asrc[(size_t)r * 4 + col] = v;
      else if (col < 8) adst[(size_t)r * 4 + (col - 4)] = v;
    }
  }
}

// ---------------------------------------------------------------- GEMM2: bf16 A, 4 LDS tiles + reg score tile
__global__ __launch_bounds__(256) void k_gemm2_att(const unsigned short* __restrict__ A,
    const unsigned short* __restrict__ Bp, unsigned char* __restrict__ h2f8,
    float* __restrict__ asrc, float* __restrict__ adst, int M){
  constexpr int K = 256, NKC = 8;
  __shared__ unsigned short Bs[64 * K];
  {
    const uint4* srcp = (const uint4*)Bp;
    uint4* dstp = (uint4*)Bs;
    for (int i = threadIdx.x; i < 2048; i += 256) dstp[i] = srcp[i];
  }
  __syncthreads();
  int wave = threadIdx.x >> 6, lane = threadIdx.x & 63;
  int quad = lane >> 4, col = lane & 15;
  int r0 = (blockIdx.x * 4 + wave) * 16;
  int rowc = min(r0 + col, M - 1);
  short8 af[NKC], sf[NKC];
#pragma unroll
  for (int kc = 0; kc < NKC; kc++){
    af[kc] = *(const short8*)(A + (size_t)rowc * K + kc * 32 + quad * 8);
    sf[kc] = *(const short8*)(Bp + (((size_t)4 * 8 + kc) * 64 + lane) * 8);
  }
  floatx4 acc[5];
#pragma unroll
  for (int nt = 0; nt < 5; nt++) acc[nt] = (floatx4){0.f, 0.f, 0.f, 0.f};
#pragma unroll
  for (int kc = 0; kc < NKC; kc++){
#pragma unroll
    for (int nt = 0; nt < 4; nt++){
      short8 bfv = *(const short8*)(&Bs[((nt * NKC + kc) * 64 + lane) * 8]);
      acc[nt] = __builtin_amdgcn_mfma_f32_16x16x32_bf16(af[kc], bfv, acc[nt], 0, 0, 0);
    }
    acc[4] = __builtin_amdgcn_mfma_f32_16x16x32_bf16(af[kc], sf[kc], acc[4], 0, 0, 0);
  }
#pragma unroll
  for (int nt = 0; nt < 4; nt++){
#pragma unroll
    for (int i = 0; i < 4; i++){
      int r = r0 + quad * 4 + i;
      if (r < M) h2f8[(size_t)r * 64 + nt * 16 + col] = f2fp8(acc[nt][i]);
    }
  }
#pragma unroll
  for (int i = 0; i < 4; i++){
    int r = r0 + quad * 4 + i;
    if (r < M){
      float v = acc[4][i];
      if (col == 0)      asrc[r] = v;
      else if (col == 1) adst[r] = v;
    }
  }
}

// ---------------------------------------------------------------- edge weight prepass L1 (fused scatter)
__global__ __launch_bounds__(256) void k_wpre1(const int4* __restrict__ epack,
    const int4* __restrict__ nodeinfo,
    const float* __restrict__ a_src, const float* __restrict__ a_dst,
    const float* __restrict__ ce, int4* __restrict__ wcsr, int E, int Eq){
  int e = blockIdx.x * 256 + threadIdx.x;
  if (e >= E) return;
  int4 c = epack[e];
  float ea = __int_as_float(c.z);
  int4 ni = nodeinfo[c.y];
  int b = (e >= Eq) + (e >= 2 * Eq) + (e >= 3 * Eq);
  int cum = b == 0 ? 0 : b == 1 ? ni.y : b == 2 ? ni.z : ni.w;
  int pos = ni.x + cum + c.w;
  float4 as4 = *(const float4*)(a_src + (size_t)c.x * 4);
  float4 ad4 = *(const float4*)(a_dst + (size_t)c.y * 4);
  float4 ce4 = *(const float4*)ce;
  float a0 = as4.x + ad4.x + ea * ce4.x; a0 = a0 > 0.f ? a0 : 0.2f * a0;
  float a1 = as4.y + ad4.y + ea * ce4.y; a1 = a1 > 0.f ? a1 : 0.2f * a1;
  float a2 = as4.z + ad4.z + ea * ce4.z; a2 = a2 > 0.f ? a2 : 0.2f * a2;
  float a3 = as4.w + ad4.w + ea * ce4.w; a3 = a3 > 0.f ? a3 : 0.2f * a3;
  unsigned u01 = pack_h2(__expf(a0), __expf(a1));
  unsigned u23 = pack_h2(__expf(a2), __expf(a3));
  wcsr[pos] = make_int4(c.x, (int)u01, (int)u23, 0);
}

// ---------------------------------------------------------------- edge weight prepass L2 (fused scatter)
__global__ __launch_bounds__(256) void k_wpre2(const int4* __restrict__ epack,
    const int4* __restrict__ nodeinfo,
    const float* __restrict__ a_src, const float* __restrict__ a_dst,
    const float* __restrict__ ce, int2* __restrict__ wcsr2, int E, int Eq){
  int e = blockIdx.x * 256 + threadIdx.x;
  if (e >= E) return;
  int4 c = epack[e];
  float ea = __int_as_float(c.z);
  int4 ni = nodeinfo[c.y];
  int b = (e >= Eq) + (e >= 2 * Eq) + (e >= 3 * Eq);
  int cum = b == 0 ? 0 : b == 1 ? ni.y : b == 2 ? ni.z : ni.w;
  int pos = ni.x + cum + c.w;
  float a = a_src[c.x] + a_dst[c.y] + ea * ce[4];
  a = a > 0.f ? a : 0.2f * a;
  wcsr2[pos] = make_int2(c.x, __float_as_int(__expf(a)));
}

// ---------------------------------------------------------------- GAT layer 1 (fp8 payload gather)
// Quarter-wave per edge; lane covers 16 channels = one uint4 of fp8.
__global__ __launch_bounds__(256) void k_gat1(
    const int* __restrict__ row_ptr, const int4* __restrict__ wcsr,
    const float* __restrict__ lattr,
    const float* __restrict__ a_src, const float* __restrict__ a_dst,
    const float* __restrict__ ce, const unsigned char* __restrict__ hpre,
    const float* __restrict__ bias, unsigned short* __restrict__ hout, int n){
  int node = blockIdx.x * 4 + (threadIdx.x >> 6);
  if (node >= n) return;
  int lane = threadIdx.x & 63;
  int q = lane >> 4, lsub = lane & 15, hq = lsub >> 2;
  int start = row_ptr[node], deg = row_ptr[node + 1] - start;
  int total = deg + 1;
  float4 as4 = *(const float4*)(a_src + (size_t)node * 4);
  float4 ad4 = *(const float4*)(a_dst + (size_t)node * 4);
  float4 ce4 = *(const float4*)ce;
  float la = lattr[node];
  float asvh = hq == 0 ? as4.x : hq == 1 ? as4.y : hq == 2 ? as4.z : as4.w;
  float advh = hq == 0 ? ad4.x : hq == 1 ? ad4.y : hq == 2 ? ad4.z : ad4.w;
  float ceh  = hq == 0 ? ce4.x : hq == 1 ? ce4.y : hq == 2 ? ce4.z : ce4.w;
  float aself = asvh + advh + la * ceh;
  aself = aself > 0.f ? aself : 0.2f * aself;
  float wself = __expf(aself);
  float2v acc2[8];
#pragma unroll
  for (int k = 0; k < 8; k++) acc2[k] = (float2v){0.f, 0.f};
  float dn = 0.f;
  for (int e = q; e < total; e += 4){
    int s; float wv;
    if (e < deg){
      int4 we = wcsr[start + e];
      s = we.x;
      unsigned wb = (hq & 2) ? (unsigned)we.z : (unsigned)we.y;
      wv = unpack_h(wb, hq & 1);
    } else { s = node; wv = wself; }
    dn += wv;
    uint4 u = *(const uint4*)(hpre + (size_t)s * 256 + lsub * 16);
    float2v w2 = (float2v){wv, wv};
    unsigned uu[4] = {u.x, u.y, u.z, u.w};
#pragma unroll
    for (int j = 0; j < 4; j++){
      float2v lo = __builtin_amdgcn_cvt_pk_f32_fp8((int)uu[j], false);
      float2v hi = __builtin_amdgcn_cvt_pk_f32_fp8((int)uu[j], true);
      acc2[2 * j]     += w2 * lo;
      acc2[2 * j + 1] += w2 * hi;
    }
  }
  dn += __shfl_xor(dn, 16, 64);
  dn += __shfl_xor(dn, 32, 64);
#pragma unroll
  for (int k = 0; k < 8; k++){
    acc2[k].x += __shfl_xor(acc2[k].x, 16, 64);
    acc2[k].x += __shfl_xor(acc2[k].x, 32, 64);
    acc2[k].y += __shfl_xor(acc2[k].y, 16, 64);
    acc2[k].y += __shfl_xor(acc2[k].y, 32, 64);
  }
  if (q == 0){
    float inv = 1.f / dn;
    float bb[16];
#pragma unroll
    for (int j = 0; j < 4; j++){
      float4 b4 = *(const float4*)(bias + lsub * 16 + j * 4);
      bb[j * 4 + 0] = b4.x; bb[j * 4 + 1] = b4.y;
      bb[j * 4 + 2] = b4.z; bb[j * 4 + 3] = b4.w;
    }
    unsigned short o[16];
#pragma unroll
    for (int k = 0; k < 16; k++){
      float av = (k & 1) ? acc2[k >> 1].y : acc2[k >> 1].x;
      float v = av * inv + bb[k];
      v = v > 0.f ? v : (__expf(v) - 1.f);
      o[k] = f2bf(v);
    }
    unsigned short* op = hout + (size_t)node * 256 + lsub * 16;
    *(uint4*)(op)     = *(uint4*)(o);
    *(uint4*)(op + 8) = *(uint4*)(o + 8);
  }
}

// ---------------------------------------------------------------- GAT layer 2 + pair projection (fp8 payload)
__global__ __launch_bounds__(256) void k_gat2(
    const int* __restrict__ row_ptr, const int2* __restrict__ wcsr2,
    const float* __restrict__ lattr,
    const float* __restrict__ a_src, const float* __restrict__ a_dst,
    const float* __restrict__ ce, const unsigned char* __restrict__ hpre,
    const float* __restrict__ bias, const float* __restrict__ Wlin,
    float* __restrict__ s1v, float* __restrict__ s2v, int n){
  int node = blockIdx.x * 4 + (threadIdx.x >> 6);
  if (node >= n) return;
  int lane = threadIdx.x & 63;
  int slot = lane >> 3, lsub = lane & 7;
  int start = row_ptr[node], deg = row_ptr[node + 1] - start;
  int total = deg + 1;
  float aself = a_src[node] + a_dst[node] + lattr[node] * ce[4];
  aself = aself > 0.f ? aself : 0.2f * aself;
  float wself = __expf(aself);
  float2v acc2[4];
#pragma unroll
  for (int k = 0; k < 4; k++) acc2[k] = (float2v){0.f, 0.f};
  float dn = 0.f;
  for (int e = slot; e < total; e += 8){
    int s; float wv;
    if (e < deg){ int2 se = wcsr2[start + e]; s = se.x; wv = __int_as_float(se.y); }
    else        { s = node; wv = wself; }
    dn += wv;
    uint2 u = *(const uint2*)(hpre + (size_t)s * 64 + lsub * 8);
    float2v w2 = (float2v){wv, wv};
    unsigned uu[2] = {u.x, u.y};
#pragma unroll
    for (int j = 0; j < 2; j++){
      float2v lo = __builtin_amdgcn_cvt_pk_f32_fp8((int)uu[j], false);
      float2v hi = __builtin_amdgcn_cvt_pk_f32_fp8((int)uu[j], true);
      acc2[2 * j]     += w2 * lo;
      acc2[2 * j + 1] += w2 * hi;
    }
  }
#pragma unroll
  for (int o = 8; o < 64; o <<= 1){
    dn += __shfl_xor(dn, o, 64);
#pragma unroll
    for (int k = 0; k < 4; k++){
      acc2[k].x += __shfl_xor(acc2[k].x, o, 64);
      acc2[k].y += __shfl_xor(acc2[k].y, o, 64);
    }
  }
  float inv = 1.f / dn;
  float t1 = 0.f, t2 = 0.f;
#pragma unroll
  for (int k = 0; k < 8; k++){
    float av = (k & 1) ? acc2[k >> 1].y : acc2[k >> 1].x;
    float v = av * inv + bias[lsub * 8 + k];
    t1 += v * Wlin[lsub * 8 + k];
    t2 += v * Wlin[64 + lsub * 8 + k];
  }
#pragma unroll
  for (int o = 1; o < 8; o <<= 1){
    t1 += __shfl_xor(t1, o, 64);
    t2 += __shfl_xor(t2, o, 64);
  }
  if (lane == 0){ s1v[node] = t1; s2v[node] = t2; }
}

// ---------------------------------------------------------------- pair head
__global__ __launch_bounds__(256) void k_pairs(const int* __restrict__ pairs,
    const float* __restrict__ s1v, const float* __restrict__ s2v,
    const float* __restrict__ blin, float* __restrict__ out, int P){
  int p = blockIdx.x * 256 + threadIdx.x;
  if (p >= P) return;
  int i = pairs[2 * p], j = pairs[2 * p + 1];
  float x = s1v[i] + s2v[j] + blin[0];
  out[p] = 1.f / (1.f + __expf(-x));
}

// ---------------------------------------------------------------- launch
extern "C" void kernel_launch(void* const* d_in, const int* in_sizes, int n_in,
                              void* d_out, int out_size, void* d_ws, size_t ws_size,
                              hipStream_t stream) {
  const float* x     = (const float*)d_in[0];
  const int*   esrc  = (const int*)  d_in[1];
  const int*   edst  = (const int*)  d_in[2];
  const float* eattr = (const float*)d_in[3];
  const int*   pairs = (const int*)  d_in[4];
  const float* W1    = (const float*)d_in[5];
  const float* We1   = (const float*)d_in[6];
  const float* as1   = (const float*)d_in[7];
  const float* ad1   = (const float*)d_in[8];
  const float* ae1   = (const float*)d_in[9];
  const float* b1    = (const float*)d_in[10];
  const float* W2    = (const float*)d_in[11];
  const float* We2   = (const float*)d_in[12];
  const float* as2   = (const float*)d_in[13];
  const float* ad2   = (const float*)d_in[14];
  const float* ae2   = (const float*)d_in[15];
  const float* b2    = (const float*)d_in[16];
  const float* Wlin  = (const float*)d_in[17];
  const float* blin  = (const float*)d_in[18];
  float* out = (float*)d_out;

  const int N = in_sizes[0] / 128;
  const int E = in_sizes[1];
  const int Eq = (E + 3) / 4;
  const int P = in_sizes[4] / 2;

  char* w = (char*)d_ws;
  size_t off = 0;
  auto alloc = [&](size_t bytes) -> size_t {
    size_t r = off; off = (off + bytes + 255) & ~(size_t)255; return r;
  };
  size_t o_degp   = alloc((size_t)N * 32);   // 4 banks of u64
  size_t zero_end = off;
  size_t o_epack  = alloc((size_t)E * 16);
  size_t o_rowptr = alloc((size_t)(N + 1) * 4);
  size_t o_bsum   = alloc(1024);
  size_t o_bofs   = alloc(1024);
  size_t o_lattr  = alloc((size_t)N * 4);
  size_t o_ninfo  = alloc((size_t)N * 16);
  size_t o_wcsr1  = alloc((size_t)E * 16);
  size_t o_wcsr2  = alloc((size_t)E * 8);
  size_t o_asrc1  = alloc((size_t)N * 16);
  size_t o_adst1  = alloc((size_t)N * 16);
  size_t o_asrc2  = alloc((size_t)N * 4);
  size_t o_adst2  = alloc((size_t)N * 4);
  size_t o_ce     = alloc(32);
  size_t o_s1     = alloc((size_t)N * 4);
  size_t o_s2     = alloc((size_t)N * 4);
  size_t o_W1p    = alloc((size_t)17 * 4 * 64 * 8 * 2);
  size_t o_W2p    = alloc((size_t)5 * 8 * 64 * 8 * 2);
  size_t o_h1f8   = alloc((size_t)N * 256);
  size_t o_h1b    = alloc((size_t)N * 256 * 2);
  size_t o_h2f8   = alloc((size_t)N * 64);
  (void)ws_size;

  unsigned long long* degp = (unsigned long long*)(w + o_degp);
  int4*  epack  = (int4*) (w + o_epack);
  int*   rowptr = (int*)  (w + o_rowptr);
  int*   bsum   = (int*)  (w + o_bsum);
  int*   bofs   = (int*)  (w + o_bofs);
  float* lattr  = (float*)(w + o_lattr);
  int4*  ninfo  = (int4*) (w + o_ninfo);
  int4*  wcsr1  = (int4*) (w + o_wcsr1);
  int2*  wcsr2  = (int2*) (w + o_wcsr2);
  float* asrc1  = (float*)(w + o_asrc1);
  float* adst1  = (float*)(w + o_adst1);
  float* asrc2  = (float*)(w + o_asrc2);
  float* adst2  = (float*)(w + o_adst2);
  float* ce     = (float*)(w + o_ce);
  float* s1v    = (float*)(w + o_s1);
  float* s2v    = (float*)(w + o_s2);
  unsigned short* W1p = (unsigned short*)(w + o_W1p);
  unsigned short* W2p = (unsigned short*)(w + o_W2p);
  unsigned char*  h1f8 = (unsigned char*)(w + o_h1f8);
  unsigned short* h1b  = (unsigned short*)(w + o_h1b);
  unsigned char*  h2f8 = (unsigned char*)(w + o_h2f8);

  hipMemsetAsync(w, 0, zero_end, stream);

  int ebl = (E + 255) / 256;
  int nbl = (N + 255) / 256;
  int wbl = (N + 3) / 4;

  // CSR metadata
  k_count<<<ebl, 256, 0, stream>>>(esrc, edst, eattr, degp, epack, E, Eq, N);
  k_scan1<<<nbl, 256, 0, stream>>>(degp, rowptr, bsum, N);
  k_scan2<<<1, 256, 0, stream>>>(bsum, bofs, nbl);
  k_scan3<<<nbl, 256, 0, stream>>>(rowptr, bofs, degp, lattr, ninfo, N, E);

  // weight packing (B1 17-tile, B2 5-tile) + edge coeffs, one dispatch
  k_prep<<<109, 64, 0, stream>>>(W1, as1, ad1, W2, as2, ad2,
                                 We1, ae1, We2, ae2, W1p, W2p, ce);

  // layer 1
  k_gemm1_att<<<(N + 63) / 64, 256, 0, stream>>>(x, W1p, h1f8, asrc1, adst1, N);
  k_wpre1<<<ebl, 256, 0, stream>>>(epack, ninfo, asrc1, adst1, ce, wcsr1, E, Eq);
  k_gat1<<<wbl, 256, 0, stream>>>(rowptr, wcsr1, lattr, asrc1, adst1, ce,
                                  h1f8, b1, h1b, N);
  // layer 2
  k_gemm2_att<<<(N + 63) / 64, 256, 0, stream>>>(h1b, W2p, h2f8, asrc2, adst2, N);
  k_wpre2<<<ebl, 256, 0, stream>>>(epack, ninfo, asrc2, adst2, ce, wcsr2, E, Eq);
  k_gat2<<<wbl, 256, 0, stream>>>(rowptr, wcsr2, lattr, asrc2, adst2, ce,
                                  h2f8, b2, Wlin, s1v, s2v, N);
  // pair head
  k_pairs<<<(P + 255) / 256, 256, 0, stream>>>(pairs, s1v, s2v, blin, out, P);
}

// Round 8
// 292.854 us; speedup vs baseline: 1.1078x; 1.0555x over previous
//
#include <hip/hip_runtime.h>
#include <hip/hip_fp16.h>
#include <math.h>

typedef __attribute__((ext_vector_type(8))) short short8;
typedef __attribute__((ext_vector_type(4))) float floatx4;
typedef __attribute__((ext_vector_type(2))) float float2v;

__device__ __forceinline__ unsigned short f2bf(float f){
  unsigned int x = __float_as_uint(f);
  unsigned int r = x + 0x7fff + ((x >> 16) & 1);   // RNE
  return (unsigned short)(r >> 16);
}
__device__ __forceinline__ unsigned char f2fp8(float v){
  int pk = __builtin_amdgcn_cvt_pk_fp8_f32(v, 0.f, 0, false);
  return (unsigned char)(pk & 0xff);
}
__device__ __forceinline__ float wsumf(float v){
#pragma unroll
  for (int o = 32; o; o >>= 1) v += __shfl_xor(v, o, 64);
  return v;
}

// ---------------------------------------------------------------- count: 4 sharded banks, 1 u64 atomic/edge
// degp[b*N+d]: bits[63:40]=count, [39:0]=sum(eattr)*2^24. rank[e]=slot within (bank,dst).
__global__ __launch_bounds__(256) void k_count(const int* __restrict__ dst,
    const float* __restrict__ eattr, unsigned long long* __restrict__ degp,
    int* __restrict__ rank, int E, int Eq, int N){
  int e = blockIdx.x * 256 + threadIdx.x;
  if (e >= E) return;
  int d = dst[e];
  float ea = eattr[e];
  int b = (e >= Eq) + (e >= 2 * Eq) + (e >= 3 * Eq);
  unsigned long long add = (1ull << 40) |
      (unsigned long long)(ea * 16777216.0f);
  unsigned long long old = atomicAdd(&degp[(size_t)b * N + d], add);
  rank[e] = (int)(old >> 40);
}

// ---------------------------------------------------------------- scans
__global__ __launch_bounds__(256) void k_scan1(const unsigned long long* __restrict__ degp,
    int* __restrict__ row_ptr, int* __restrict__ bsum, int n){
  __shared__ int sm[2][256];
  int tid = threadIdx.x, gid = blockIdx.x * 256 + tid;
  int v = 0;
  if (gid < n){
#pragma unroll
    for (int b = 0; b < 4; b++) v += (int)(degp[(size_t)b * n + gid] >> 40);
  }
  sm[0][tid] = v; __syncthreads();
  int pin = 0;
  for (int off = 1; off < 256; off <<= 1){
    int t = sm[pin][tid];
    if (tid >= off) t += sm[pin][tid - off];
    sm[pin ^ 1][tid] = t; pin ^= 1; __syncthreads();
  }
  int incl = sm[pin][tid];
  if (gid < n) row_ptr[gid] = incl - v;
  if (tid == 255) bsum[blockIdx.x] = incl;
}

__global__ __launch_bounds__(256) void k_scan2(const int* __restrict__ bsum,
    int* __restrict__ bofs, int nb){
  __shared__ int sm[2][256];
  int tid = threadIdx.x;
  int v = (tid < nb) ? bsum[tid] : 0;
  sm[0][tid] = v; __syncthreads();
  int pin = 0;
  for (int off = 1; off < 256; off <<= 1){
    int t = sm[pin][tid];
    if (tid >= off) t += sm[pin][tid - off];
    sm[pin ^ 1][tid] = t; pin ^= 1; __syncthreads();
  }
  bofs[tid] = sm[pin][tid] - v;
}

__global__ __launch_bounds__(256) void k_scan3(int* __restrict__ row_ptr,
    const int* __restrict__ bofs, const unsigned long long* __restrict__ degp,
    float* __restrict__ lattr, int4* __restrict__ nodeinfo, int n, int E){
  int gid = blockIdx.x * 256 + threadIdx.x;
  if (gid >= n) return;
  int rp = row_ptr[gid] + bofs[gid >> 8];
  row_ptr[gid] = rp;
  const unsigned long long M40 = (1ull << 40) - 1;
  unsigned long long p0 = degp[gid];
  unsigned long long p1 = degp[(size_t)n + gid];
  unsigned long long p2 = degp[(size_t)2 * n + gid];
  unsigned long long p3 = degp[(size_t)3 * n + gid];
  int d0 = (int)(p0 >> 40), d1 = (int)(p1 >> 40), d2 = (int)(p2 >> 40), d3 = (int)(p3 >> 40);
  float dtot = (float)(d0 + d1 + d2 + d3);
  float s = ((float)(p0 & M40) + (float)(p1 & M40) + (float)(p2 & M40) + (float)(p3 & M40))
            * (1.0f / 16777216.0f);
  lattr[gid] = s / fmaxf(dtot, 1.0f);
  nodeinfo[gid] = make_int4(rp, d0, d0 + d1, d0 + d1 + d2);
  if (gid == 0) row_ptr[n] = E;
}

// ---------------------------------------------------------------- scatter: CSR-ordered {src, ea} (8 B)
__global__ __launch_bounds__(256) void k_scatter(const int* __restrict__ src,
    const int* __restrict__ dst, const float* __restrict__ eattr,
    const int* __restrict__ rank, const int4* __restrict__ nodeinfo,
    int2* __restrict__ csr, int E, int Eq){
  int e = blockIdx.x * 256 + threadIdx.x;
  if (e >= E) return;
  int d = dst[e];
  int4 ni = nodeinfo[d];
  int b = (e >= Eq) + (e >= 2 * Eq) + (e >= 3 * Eq);
  int cum = b == 0 ? 0 : b == 1 ? ni.y : b == 2 ? ni.z : ni.w;
  int pos = ni.x + cum + rank[e];
  csr[pos] = make_int2(src[e], __float_as_int(eattr[e]));
}

// ---------------------------------------------------------------- prep: pack B1 (17 tiles), B2 (5 tiles), ce
__global__ void k_prep(const float* __restrict__ W1, const float* __restrict__ as1,
    const float* __restrict__ ad1, const float* __restrict__ W2,
    const float* __restrict__ as2, const float* __restrict__ ad2,
    const float* __restrict__ We1, const float* __restrict__ ae1,
    const float* __restrict__ We2, const float* __restrict__ ae2,
    unsigned short* __restrict__ W1p, unsigned short* __restrict__ W2p,
    float* __restrict__ ce){
  int b = blockIdx.x, lane = threadIdx.x;
  if (b < 68){                                   // gemm1 tiles: nt 0..16, kc 0..3
    int nt = b >> 2, kc = b & 3;
    int col = lane & 15, krow = kc * 32 + (lane >> 4) * 8;
    unsigned short tmp[8];
    if (nt < 16){
#pragma unroll
      for (int j = 0; j < 8; j++) tmp[j] = f2bf(W1[(size_t)(krow + j) * 256 + nt * 16 + col]);
    } else {
#pragma unroll
      for (int j = 0; j < 8; j++){
        float v = 0.f;
        if (col < 8){
          const float* av = (col < 4) ? as1 : ad1;
          int h = col & 3;
          for (int c = 0; c < 64; c++)
            v += W1[(size_t)(krow + j) * 256 + h * 64 + c] * av[h * 64 + c];
        }
        tmp[j] = f2bf(v);
      }
    }
    unsigned short* dstp = W1p + (((size_t)nt * 4 + kc) * 64 + lane) * 8;
    *(ushort4*)(dstp)     = make_ushort4(tmp[0], tmp[1], tmp[2], tmp[3]);
    *(ushort4*)(dstp + 4) = make_ushort4(tmp[4], tmp[5], tmp[6], tmp[7]);
  } else if (b < 108){                           // gemm2 tiles: nt 0..4, kc 0..7
    int bb = b - 68;
    int nt = bb >> 3, kc = bb & 7;
    int col = lane & 15, krow = kc * 32 + (lane >> 4) * 8;
    unsigned short tmp[8];
    if (nt < 4){
#pragma unroll
      for (int j = 0; j < 8; j++) tmp[j] = f2bf(W2[(size_t)(krow + j) * 64 + nt * 16 + col]);
    } else {
#pragma unroll
      for (int j = 0; j < 8; j++){
        float v = 0.f;
        if (col < 2){
          const float* av = (col == 0) ? as2 : ad2;
          for (int c = 0; c < 64; c++)
            v += W2[(size_t)(krow + j) * 64 + c] * av[c];
        }
        tmp[j] = f2bf(v);
      }
    }
    unsigned short* dstp = W2p + (((size_t)nt * 8 + kc) * 64 + lane) * 8;
    *(ushort4*)(dstp)     = make_ushort4(tmp[0], tmp[1], tmp[2], tmp[3]);
    *(ushort4*)(dstp + 4) = make_ushort4(tmp[4], tmp[5], tmp[6], tmp[7]);
  } else {                                       // ce
    float p0 = We1[lane]       * ae1[lane];
    float p1 = We1[64 + lane]  * ae1[64 + lane];
    float p2 = We1[128 + lane] * ae1[128 + lane];
    float p3 = We1[192 + lane] * ae1[192 + lane];
    float p4 = We2[lane]       * ae2[lane];
    p0 = wsumf(p0); p1 = wsumf(p1); p2 = wsumf(p2); p3 = wsumf(p3); p4 = wsumf(p4);
    if (lane == 0){ ce[0] = p0; ce[1] = p1; ce[2] = p2; ce[3] = p3; ce[4] = p4; }
  }
}

// ---------------------------------------------------------------- GEMM1: fp32 A, 16 LDS tiles + reg score tile
__global__ __launch_bounds__(256) void k_gemm1_att(const float* __restrict__ A,
    const unsigned short* __restrict__ Bp, unsigned char* __restrict__ h1f8,
    float* __restrict__ asrc, float* __restrict__ adst, int M){
  constexpr int K = 128, NKC = 4;
  __shared__ unsigned short Bs[256 * K];
  {
    const uint4* srcp = (const uint4*)Bp;
    uint4* dstp = (uint4*)Bs;
    for (int i = threadIdx.x; i < 4096; i += 256) dstp[i] = srcp[i];
  }
  __syncthreads();
  int wave = threadIdx.x >> 6, lane = threadIdx.x & 63;
  int quad = lane >> 4, col = lane & 15;
  int r0 = (blockIdx.x * 4 + wave) * 16;
  int rowc = min(r0 + col, M - 1);
  short8 af[NKC], sf[NKC];
#pragma unroll
  for (int kc = 0; kc < NKC; kc++){
    float4 a0 = *(const float4*)(A + (size_t)rowc * K + kc * 32 + quad * 8);
    float4 a1 = *(const float4*)(A + (size_t)rowc * K + kc * 32 + quad * 8 + 4);
    short8 t;
    t[0] = (short)f2bf(a0.x); t[1] = (short)f2bf(a0.y);
    t[2] = (short)f2bf(a0.z); t[3] = (short)f2bf(a0.w);
    t[4] = (short)f2bf(a1.x); t[5] = (short)f2bf(a1.y);
    t[6] = (short)f2bf(a1.z); t[7] = (short)f2bf(a1.w);
    af[kc] = t;
    sf[kc] = *(const short8*)(Bp + (((size_t)16 * 4 + kc) * 64 + lane) * 8);
  }
  floatx4 acc[17];
#pragma unroll
  for (int nt = 0; nt < 17; nt++) acc[nt] = (floatx4){0.f, 0.f, 0.f, 0.f};
#pragma unroll
  for (int kc = 0; kc < NKC; kc++){
#pragma unroll
    for (int nt = 0; nt < 16; nt++){
      short8 bfv = *(const short8*)(&Bs[((nt * NKC + kc) * 64 + lane) * 8]);
      acc[nt] = __builtin_amdgcn_mfma_f32_16x16x32_bf16(af[kc], bfv, acc[nt], 0, 0, 0);
    }
    acc[16] = __builtin_amdgcn_mfma_f32_16x16x32_bf16(af[kc], sf[kc], acc[16], 0, 0, 0);
  }
#pragma unroll
  for (int nt = 0; nt < 16; nt++){
#pragma unroll
    for (int i = 0; i < 4; i++){
      int r = r0 + quad * 4 + i;
      if (r < M) h1f8[(size_t)r * 256 + nt * 16 + col] = f2fp8(acc[nt][i]);
    }
  }
#pragma unroll
  for (int i = 0; i < 4; i++){
    int r = r0 + quad * 4 + i;
    if (r < M){
      float v = acc[16][i];
      if (col < 4)      asrc[(size_t)r * 4 + col] = v;
      else if (col < 8) adst[(size_t)r * 4 + (col - 4)] = v;
    }
  }
}

// ---------------------------------------------------------------- GEMM2: bf16 A, 4 LDS tiles + reg score tile
__global__ __launch_bounds__(256) void k_gemm2_att(const unsigned short* __restrict__ A,
    const unsigned short* __restrict__ Bp, unsigned char* __restrict__ h2f8,
    float* __restrict__ asrc, float* __restrict__ adst, int M){
  constexpr int K = 256, NKC = 8;
  __shared__ unsigned short Bs[64 * K];
  {
    const uint4* srcp = (const uint4*)Bp;
    uint4* dstp = (uint4*)Bs;
    for (int i = threadIdx.x; i < 2048; i += 256) dstp[i] = srcp[i];
  }
  __syncthreads();
  int wave = threadIdx.x >> 6, lane = threadIdx.x & 63;
  int quad = lane >> 4, col = lane & 15;
  int r0 = (blockIdx.x * 4 + wave) * 16;
  int rowc = min(r0 + col, M - 1);
  short8 af[NKC], sf[NKC];
#pragma unroll
  for (int kc = 0; kc < NKC; kc++){
    af[kc] = *(const short8*)(A + (size_t)rowc * K + kc * 32 + quad * 8);
    sf[kc] = *(const short8*)(Bp + (((size_t)4 * 8 + kc) * 64 + lane) * 8);
  }
  floatx4 acc[5];
#pragma unroll
  for (int nt = 0; nt < 5; nt++) acc[nt] = (floatx4){0.f, 0.f, 0.f, 0.f};
#pragma unroll
  for (int kc = 0; kc < NKC; kc++){
#pragma unroll
    for (int nt = 0; nt < 4; nt++){
      short8 bfv = *(const short8*)(&Bs[((nt * NKC + kc) * 64 + lane) * 8]);
      acc[nt] = __builtin_amdgcn_mfma_f32_16x16x32_bf16(af[kc], bfv, acc[nt], 0, 0, 0);
    }
    acc[4] = __builtin_amdgcn_mfma_f32_16x16x32_bf16(af[kc], sf[kc], acc[4], 0, 0, 0);
  }
#pragma unroll
  for (int nt = 0; nt < 4; nt++){
#pragma unroll
    for (int i = 0; i < 4; i++){
      int r = r0 + quad * 4 + i;
      if (r < M) h2f8[(size_t)r * 64 + nt * 16 + col] = f2fp8(acc[nt][i]);
    }
  }
#pragma unroll
  for (int i = 0; i < 4; i++){
    int r = r0 + quad * 4 + i;
    if (r < M){
      float v = acc[4][i];
      if (col == 0)      asrc[r] = v;
      else if (col == 1) adst[r] = v;
    }
  }
}

// ---------------------------------------------------------------- GAT layer 1 (inline softmax weights, fp8 payload)
// Quarter-wave per edge; lane covers 16 channels.
__global__ __launch_bounds__(256) void k_gat1(
    const int* __restrict__ row_ptr, const int2* __restrict__ csr,
    const float* __restrict__ lattr,
    const float* __restrict__ a_src, const float* __restrict__ a_dst,
    const float* __restrict__ ce, const unsigned char* __restrict__ hpre,
    const float* __restrict__ bias, unsigned short* __restrict__ hout, int n){
  int node = blockIdx.x * 4 + (threadIdx.x >> 6);
  if (node >= n) return;
  int lane = threadIdx.x & 63;
  int q = lane >> 4, lsub = lane & 15, hq = lsub >> 2;
  int start = row_ptr[node], deg = row_ptr[node + 1] - start;
  int total = deg + 1;
  float4 as4 = *(const float4*)(a_src + (size_t)node * 4);
  float4 ad4 = *(const float4*)(a_dst + (size_t)node * 4);
  float4 ce4 = *(const float4*)ce;
  float la = lattr[node];
  float asvh = hq == 0 ? as4.x : hq == 1 ? as4.y : hq == 2 ? as4.z : as4.w;
  float advh = hq == 0 ? ad4.x : hq == 1 ? ad4.y : hq == 2 ? ad4.z : ad4.w;
  float ceh  = hq == 0 ? ce4.x : hq == 1 ? ce4.y : hq == 2 ? ce4.z : ce4.w;
  float aself = asvh + advh + la * ceh;
  aself = aself > 0.f ? aself : 0.2f * aself;
  float wself = __expf(aself);
  float2v acc2[8];
#pragma unroll
  for (int k = 0; k < 8; k++) acc2[k] = (float2v){0.f, 0.f};
  float dn = 0.f;
  for (int e = q; e < total; e += 4){
    int s; float wv;
    if (e < deg){
      int2 se = csr[start + e];
      s = se.x;
      float ea = __int_as_float(se.y);
      float a = a_src[(size_t)s * 4 + hq] + advh + ea * ceh;
      a = a > 0.f ? a : 0.2f * a;
      wv = __expf(a);
    } else { s = node; wv = wself; }
    dn += wv;
    uint4 u = *(const uint4*)(hpre + (size_t)s * 256 + lsub * 16);
    float2v w2 = (float2v){wv, wv};
    unsigned uu[4] = {u.x, u.y, u.z, u.w};
#pragma unroll
    for (int j = 0; j < 4; j++){
      float2v lo = __builtin_amdgcn_cvt_pk_f32_fp8((int)uu[j], false);
      float2v hi = __builtin_amdgcn_cvt_pk_f32_fp8((int)uu[j], true);
      acc2[2 * j]     += w2 * lo;
      acc2[2 * j + 1] += w2 * hi;
    }
  }
  dn += __shfl_xor(dn, 16, 64);
  dn += __shfl_xor(dn, 32, 64);
#pragma unroll
  for (int k = 0; k < 8; k++){
    acc2[k].x += __shfl_xor(acc2[k].x, 16, 64);
    acc2[k].x += __shfl_xor(acc2[k].x, 32, 64);
    acc2[k].y += __shfl_xor(acc2[k].y, 16, 64);
    acc2[k].y += __shfl_xor(acc2[k].y, 32, 64);
  }
  if (q == 0){
    float inv = 1.f / dn;
    float bb[16];
#pragma unroll
    for (int j = 0; j < 4; j++){
      float4 b4 = *(const float4*)(bias + lsub * 16 + j * 4);
      bb[j * 4 + 0] = b4.x; bb[j * 4 + 1] = b4.y;
      bb[j * 4 + 2] = b4.z; bb[j * 4 + 3] = b4.w;
    }
    unsigned short o[16];
#pragma unroll
    for (int k = 0; k < 16; k++){
      float av = (k & 1) ? acc2[k >> 1].y : acc2[k >> 1].x;
      float v = av * inv + bb[k];
      v = v > 0.f ? v : (__expf(v) - 1.f);
      o[k] = f2bf(v);
    }
    unsigned short* op = hout + (size_t)node * 256 + lsub * 16;
    *(uint4*)(op)     = *(uint4*)(o);
    *(uint4*)(op + 8) = *(uint4*)(o + 8);
  }
}

// ---------------------------------------------------------------- GAT layer 2 + pair projection (inline weights)
__global__ __launch_bounds__(256) void k_gat2(
    const int* __restrict__ row_ptr, const int2* __restrict__ csr,
    const float* __restrict__ lattr,
    const float* __restrict__ a_src, const float* __restrict__ a_dst,
    const float* __restrict__ ce, const unsigned char* __restrict__ hpre,
    const float* __restrict__ bias, const float* __restrict__ Wlin,
    float* __restrict__ s1v, float* __restrict__ s2v, int n){
  int node = blockIdx.x * 4 + (threadIdx.x >> 6);
  if (node >= n) return;
  int lane = threadIdx.x & 63;
  int slot = lane >> 3, lsub = lane & 7;
  int start = row_ptr[node], deg = row_ptr[node + 1] - start;
  int total = deg + 1;
  float adn = a_dst[node], c = ce[4];
  float aself = a_src[node] + adn + lattr[node] * c;
  aself = aself > 0.f ? aself : 0.2f * aself;
  float wself = __expf(aself);
  float2v acc2[4];
#pragma unroll
  for (int k = 0; k < 4; k++) acc2[k] = (float2v){0.f, 0.f};
  float dn = 0.f;
  for (int e = slot; e < total; e += 8){
    int s; float wv;
    if (e < deg){
      int2 se = csr[start + e];
      s = se.x;
      float ea = __int_as_float(se.y);
      float a = a_src[s] + adn + ea * c;
      a = a > 0.f ? a : 0.2f * a;
      wv = __expf(a);
    } else { s = node; wv = wself; }
    dn += wv;
    uint2 u = *(const uint2*)(hpre + (size_t)s * 64 + lsub * 8);
    float2v w2 = (float2v){wv, wv};
    unsigned uu[2] = {u.x, u.y};
#pragma unroll
    for (int j = 0; j < 2; j++){
      float2v lo = __builtin_amdgcn_cvt_pk_f32_fp8((int)uu[j], false);
      float2v hi = __builtin_amdgcn_cvt_pk_f32_fp8((int)uu[j], true);
      acc2[2 * j]     += w2 * lo;
      acc2[2 * j + 1] += w2 * hi;
    }
  }
#pragma unroll
  for (int o = 8; o < 64; o <<= 1){
    dn += __shfl_xor(dn, o, 64);
#pragma unroll
    for (int k = 0; k < 4; k++){
      acc2[k].x += __shfl_xor(acc2[k].x, o, 64);
      acc2[k].y += __shfl_xor(acc2[k].y, o, 64);
    }
  }
  float inv = 1.f / dn;
  float t1 = 0.f, t2 = 0.f;
#pragma unroll
  for (int k = 0; k < 8; k++){
    float av = (k & 1) ? acc2[k >> 1].y : acc2[k >> 1].x;
    float v = av * inv + bias[lsub * 8 + k];
    t1 += v * Wlin[lsub * 8 + k];
    t2 += v * Wlin[64 + lsub * 8 + k];
  }
#pragma unroll
  for (int o = 1; o < 8; o <<= 1){
    t1 += __shfl_xor(t1, o, 64);
    t2 += __shfl_xor(t2, o, 64);
  }
  if (lane == 0){ s1v[node] = t1; s2v[node] = t2; }
}

// ---------------------------------------------------------------- pair head
__global__ __launch_bounds__(256) void k_pairs(const int* __restrict__ pairs,
    const float* __restrict__ s1v, const float* __restrict__ s2v,
    const float* __restrict__ blin, float* __restrict__ out, int P){
  int p = blockIdx.x * 256 + threadIdx.x;
  if (p >= P) return;
  int i = pairs[2 * p], j = pairs[2 * p + 1];
  float x = s1v[i] + s2v[j] + blin[0];
  out[p] = 1.f / (1.f + __expf(-x));
}

// ---------------------------------------------------------------- launch
extern "C" void kernel_launch(void* const* d_in, const int* in_sizes, int n_in,
                              void* d_out, int out_size, void* d_ws, size_t ws_size,
                              hipStream_t stream) {
  const float* x     = (const float*)d_in[0];
  const int*   esrc  = (const int*)  d_in[1];
  const int*   edst  = (const int*)  d_in[2];
  const float* eattr = (const float*)d_in[3];
  const int*   pairs = (const int*)  d_in[4];
  const float* W1    = (const float*)d_in[5];
  const float* We1   = (const float*)d_in[6];
  const float* as1   = (const float*)d_in[7];
  const float* ad1   = (const float*)d_in[8];
  const float* ae1   = (const float*)d_in[9];
  const float* b1    = (const float*)d_in[10];
  const float* W2    = (const float*)d_in[11];
  const float* We2   = (const float*)d_in[12];
  const float* as2   = (const float*)d_in[13];
  const float* ad2   = (const float*)d_in[14];
  const float* ae2   = (const float*)d_in[15];
  const float* b2    = (const float*)d_in[16];
  const float* Wlin  = (const float*)d_in[17];
  const float* blin  = (const float*)d_in[18];
  float* out = (float*)d_out;

  const int N = in_sizes[0] / 128;
  const int E = in_sizes[1];
  const int Eq = (E + 3) / 4;
  const int P = in_sizes[4] / 2;

  char* w = (char*)d_ws;
  size_t off = 0;
  auto alloc = [&](size_t bytes) -> size_t {
    size_t r = off; off = (off + bytes + 255) & ~(size_t)255; return r;
  };
  size_t o_degp   = alloc((size_t)N * 32);   // 4 banks of u64
  size_t zero_end = off;
  size_t o_rank   = alloc((size_t)E * 4);
  size_t o_rowptr = alloc((size_t)(N + 1) * 4);
  size_t o_bsum   = alloc(1024);
  size_t o_bofs   = alloc(1024);
  size_t o_lattr  = alloc((size_t)N * 4);
  size_t o_ninfo  = alloc((size_t)N * 16);
  size_t o_csr    = alloc((size_t)E * 8);
  size_t o_asrc1  = alloc((size_t)N * 16);
  size_t o_adst1  = alloc((size_t)N * 16);
  size_t o_asrc2  = alloc((size_t)N * 4);
  size_t o_adst2  = alloc((size_t)N * 4);
  size_t o_ce     = alloc(32);
  size_t o_s1     = alloc((size_t)N * 4);
  size_t o_s2     = alloc((size_t)N * 4);
  size_t o_W1p    = alloc((size_t)17 * 4 * 64 * 8 * 2);
  size_t o_W2p    = alloc((size_t)5 * 8 * 64 * 8 * 2);
  size_t o_h1f8   = alloc((size_t)N * 256);
  size_t o_h1b    = alloc((size_t)N * 256 * 2);
  size_t o_h2f8   = alloc((size_t)N * 64);
  (void)ws_size;

  unsigned long long* degp = (unsigned long long*)(w + o_degp);
  int*   rank   = (int*)  (w + o_rank);
  int*   rowptr = (int*)  (w + o_rowptr);
  int*   bsum   = (int*)  (w + o_bsum);
  int*   bofs   = (int*)  (w + o_bofs);
  float* lattr  = (float*)(w + o_lattr);
  int4*  ninfo  = (int4*) (w + o_ninfo);
  int2*  csr    = (int2*) (w + o_csr);
  float* asrc1  = (float*)(w + o_asrc1);
  float* adst1  = (float*)(w + o_adst1);
  float* asrc2  = (float*)(w + o_asrc2);
  float* adst2  = (float*)(w + o_adst2);
  float* ce     = (float*)(w + o_ce);
  float* s1v    = (float*)(w + o_s1);
  float* s2v    = (float*)(w + o_s2);
  unsigned short* W1p = (unsigned short*)(w + o_W1p);
  unsigned short* W2p = (unsigned short*)(w + o_W2p);
  unsigned char*  h1f8 = (unsigned char*)(w + o_h1f8);
  unsigned short* h1b  = (unsigned short*)(w + o_h1b);
  unsigned char*  h2f8 = (unsigned char*)(w + o_h2f8);

  hipMemsetAsync(w, 0, zero_end, stream);

  int ebl = (E + 255) / 256;
  int nbl = (N + 255) / 256;
  int wbl = (N + 3) / 4;

  // CSR build
  k_count<<<ebl, 256, 0, stream>>>(edst, eattr, degp, rank, E, Eq, N);
  k_scan1<<<nbl, 256, 0, stream>>>(degp, rowptr, bsum, N);
  k_scan2<<<1, 256, 0, stream>>>(bsum, bofs, nbl);
  k_scan3<<<nbl, 256, 0, stream>>>(rowptr, bofs, degp, lattr, ninfo, N, E);
  k_scatter<<<ebl, 256, 0, stream>>>(esrc, edst, eattr, rank, ninfo, csr, E, Eq);

  // weight packing + edge coeffs
  k_prep<<<109, 64, 0, stream>>>(W1, as1, ad1, W2, as2, ad2,
                                 We1, ae1, We2, ae2, W1p, W2p, ce);

  // layer 1
  k_gemm1_att<<<(N + 63) / 64, 256, 0, stream>>>(x, W1p, h1f8, asrc1, adst1, N);
  k_gat1<<<wbl, 256, 0, stream>>>(rowptr, csr, lattr, asrc1, adst1, ce,
                                  h1f8, b1, h1b, N);
  // layer 2
  k_gemm2_att<<<(N + 63) / 64, 256, 0, stream>>>(h1b, W2p, h2f8, asrc2, adst2, N);
  k_gat2<<<wbl, 256, 0, stream>>>(rowptr, csr, lattr, asrc2, adst2, ce,
                                  h2f8, b2, Wlin, s1v, s2v, N);
  // pair head
  k_pairs<<<(P + 255) / 256, 256, 0, stream>>>(pairs, s1v, s2v, blin, out, P);
}

// Round 9
// 280.197 us; speedup vs baseline: 1.1578x; 1.0452x over previous
//
#include <hip/hip_runtime.h>
#include <hip/hip_fp16.h>
#include <math.h>

typedef __attribute__((ext_vector_type(8))) short short8;
typedef __attribute__((ext_vector_type(4))) float floatx4;
typedef __attribute__((ext_vector_type(2))) float float2v;

__device__ __forceinline__ unsigned short f2bf(float f){
  unsigned int x = __float_as_uint(f);
  unsigned int r = x + 0x7fff + ((x >> 16) & 1);   // RNE
  return (unsigned short)(r >> 16);
}
__device__ __forceinline__ unsigned char f2fp8(float v){
  int pk = __builtin_amdgcn_cvt_pk_fp8_f32(v, 0.f, 0, false);
  return (unsigned char)(pk & 0xff);
}
__device__ __forceinline__ float wsumf(float v){
#pragma unroll
  for (int o = 32; o; o >>= 1) v += __shfl_xor(v, o, 64);
  return v;
}

// ---------------------------------------------------------------- count: 8 XCD-local banks (bank = blockIdx&7)
// degp[b*N+d]: bits[63:40]=count, [39:0]=sum(eattr)*2^24. rank[e]=slot within (bank,dst).
__global__ __launch_bounds__(256) void k_count(const int* __restrict__ dst,
    const float* __restrict__ eattr, unsigned long long* __restrict__ degp,
    int* __restrict__ rank, int E, int N){
  int e = blockIdx.x * 256 + threadIdx.x;
  if (e >= E) return;
  int b = blockIdx.x & 7;
  int d = dst[e];
  unsigned long long add = (1ull << 40) |
      (unsigned long long)(eattr[e] * 16777216.0f);
  unsigned long long old = atomicAdd(&degp[(size_t)b * N + d], add);
  rank[e] = (int)(old >> 40);
}

// ---------------------------------------------------------------- scans
__global__ __launch_bounds__(256) void k_scan1(const unsigned long long* __restrict__ degp,
    int* __restrict__ row_ptr, int* __restrict__ bsum, int n){
  __shared__ int sm[2][256];
  int tid = threadIdx.x, gid = blockIdx.x * 256 + tid;
  int v = 0;
  if (gid < n){
#pragma unroll
    for (int b = 0; b < 8; b++) v += (int)(degp[(size_t)b * n + gid] >> 40);
  }
  sm[0][tid] = v; __syncthreads();
  int pin = 0;
  for (int off = 1; off < 256; off <<= 1){
    int t = sm[pin][tid];
    if (tid >= off) t += sm[pin][tid - off];
    sm[pin ^ 1][tid] = t; pin ^= 1; __syncthreads();
  }
  int incl = sm[pin][tid];
  if (gid < n) row_ptr[gid] = incl - v;
  if (tid == 255) bsum[blockIdx.x] = incl;
}

__global__ __launch_bounds__(256) void k_scan2(const int* __restrict__ bsum,
    int* __restrict__ bofs, int nb){
  __shared__ int sm[2][256];
  int tid = threadIdx.x;
  int v = (tid < nb) ? bsum[tid] : 0;
  sm[0][tid] = v; __syncthreads();
  int pin = 0;
  for (int off = 1; off < 256; off <<= 1){
    int t = sm[pin][tid];
    if (tid >= off) t += sm[pin][tid - off];
    sm[pin ^ 1][tid] = t; pin ^= 1; __syncthreads();
  }
  bofs[tid] = sm[pin][tid] - v;
}

// scan3: row_ptr finalize; base[gid*8+b] = row_ptr + cumulative bank offset; lattr.
__global__ __launch_bounds__(256) void k_scan3(int* __restrict__ row_ptr,
    const int* __restrict__ bofs, const unsigned long long* __restrict__ degp,
    float* __restrict__ lattr, int* __restrict__ base, int n, int E){
  int gid = blockIdx.x * 256 + threadIdx.x;
  if (gid >= n) return;
  int rp = row_ptr[gid] + bofs[gid >> 8];
  row_ptr[gid] = rp;
  const unsigned long long M40 = (1ull << 40) - 1;
  int cum = 0; float s = 0.f;
  int bb[8];
#pragma unroll
  for (int b = 0; b < 8; b++){
    unsigned long long p = degp[(size_t)b * n + gid];
    bb[b] = rp + cum;
    cum += (int)(p >> 40);
    s += (float)(p & M40);
  }
  lattr[gid] = (s * (1.0f / 16777216.0f)) / fmaxf((float)cum, 1.0f);
  int4* bp = (int4*)(base + (size_t)gid * 8);
  bp[0] = make_int4(bb[0], bb[1], bb[2], bb[3]);
  bp[1] = make_int4(bb[4], bb[5], bb[6], bb[7]);
  if (gid == 0) row_ptr[n] = E;
}

// ---------------------------------------------------------------- scatter: CSR-ordered {src, ea} (8 B)
__global__ __launch_bounds__(256) void k_scatter(const int* __restrict__ src,
    const int* __restrict__ dst, const float* __restrict__ eattr,
    const int* __restrict__ rank, const int* __restrict__ base,
    int2* __restrict__ csr, int E){
  int e = blockIdx.x * 256 + threadIdx.x;
  if (e >= E) return;
  int b = blockIdx.x & 7;
  int d = dst[e];
  int pos = base[(size_t)d * 8 + b] + rank[e];
  csr[pos] = make_int2(src[e], __float_as_int(eattr[e]));
}

// ---------------------------------------------------------------- prep: pack B1 (17 tiles), B2 (5 tiles), ce
__global__ void k_prep(const float* __restrict__ W1, const float* __restrict__ as1,
    const float* __restrict__ ad1, const float* __restrict__ W2,
    const float* __restrict__ as2, const float* __restrict__ ad2,
    const float* __restrict__ We1, const float* __restrict__ ae1,
    const float* __restrict__ We2, const float* __restrict__ ae2,
    unsigned short* __restrict__ W1p, unsigned short* __restrict__ W2p,
    float* __restrict__ ce){
  int b = blockIdx.x, lane = threadIdx.x;
  if (b < 68){
    int nt = b >> 2, kc = b & 3;
    int col = lane & 15, krow = kc * 32 + (lane >> 4) * 8;
    unsigned short tmp[8];
    if (nt < 16){
#pragma unroll
      for (int j = 0; j < 8; j++) tmp[j] = f2bf(W1[(size_t)(krow + j) * 256 + nt * 16 + col]);
    } else {
#pragma unroll
      for (int j = 0; j < 8; j++){
        float v = 0.f;
        if (col < 8){
          const float* av = (col < 4) ? as1 : ad1;
          int h = col & 3;
          for (int c = 0; c < 64; c++)
            v += W1[(size_t)(krow + j) * 256 + h * 64 + c] * av[h * 64 + c];
        }
        tmp[j] = f2bf(v);
      }
    }
    unsigned short* dstp = W1p + (((size_t)nt * 4 + kc) * 64 + lane) * 8;
    *(ushort4*)(dstp)     = make_ushort4(tmp[0], tmp[1], tmp[2], tmp[3]);
    *(ushort4*)(dstp + 4) = make_ushort4(tmp[4], tmp[5], tmp[6], tmp[7]);
  } else if (b < 108){
    int bb = b - 68;
    int nt = bb >> 3, kc = bb & 7;
    int col = lane & 15, krow = kc * 32 + (lane >> 4) * 8;
    unsigned short tmp[8];
    if (nt < 4){
#pragma unroll
      for (int j = 0; j < 8; j++) tmp[j] = f2bf(W2[(size_t)(krow + j) * 64 + nt * 16 + col]);
    } else {
#pragma unroll
      for (int j = 0; j < 8; j++){
        float v = 0.f;
        if (col < 2){
          const float* av = (col == 0) ? as2 : ad2;
          for (int c = 0; c < 64; c++)
            v += W2[(size_t)(krow + j) * 64 + c] * av[c];
        }
        tmp[j] = f2bf(v);
      }
    }
    unsigned short* dstp = W2p + (((size_t)nt * 8 + kc) * 64 + lane) * 8;
    *(ushort4*)(dstp)     = make_ushort4(tmp[0], tmp[1], tmp[2], tmp[3]);
    *(ushort4*)(dstp + 4) = make_ushort4(tmp[4], tmp[5], tmp[6], tmp[7]);
  } else {
    float p0 = We1[lane]       * ae1[lane];
    float p1 = We1[64 + lane]  * ae1[64 + lane];
    float p2 = We1[128 + lane] * ae1[128 + lane];
    float p3 = We1[192 + lane] * ae1[192 + lane];
    float p4 = We2[lane]       * ae2[lane];
    p0 = wsumf(p0); p1 = wsumf(p1); p2 = wsumf(p2); p3 = wsumf(p3); p4 = wsumf(p4);
    if (lane == 0){ ce[0] = p0; ce[1] = p1; ce[2] = p2; ce[3] = p3; ce[4] = p4; }
  }
}

// ---------------------------------------------------------------- GEMM1: fp32 A, 16 LDS tiles + reg score tile
__global__ __launch_bounds__(256) void k_gemm1_att(const float* __restrict__ A,
    const unsigned short* __restrict__ Bp, unsigned char* __restrict__ h1f8,
    float* __restrict__ asrc, float* __restrict__ adst, int M){
  constexpr int K = 128, NKC = 4;
  __shared__ unsigned short Bs[256 * K];
  {
    const uint4* srcp = (const uint4*)Bp;
    uint4* dstp = (uint4*)Bs;
    for (int i = threadIdx.x; i < 4096; i += 256) dstp[i] = srcp[i];
  }
  __syncthreads();
  int wave = threadIdx.x >> 6, lane = threadIdx.x & 63;
  int quad = lane >> 4, col = lane & 15;
  int r0 = (blockIdx.x * 4 + wave) * 16;
  int rowc = min(r0 + col, M - 1);
  short8 af[NKC], sf[NKC];
#pragma unroll
  for (int kc = 0; kc < NKC; kc++){
    float4 a0 = *(const float4*)(A + (size_t)rowc * K + kc * 32 + quad * 8);
    float4 a1 = *(const float4*)(A + (size_t)rowc * K + kc * 32 + quad * 8 + 4);
    short8 t;
    t[0] = (short)f2bf(a0.x); t[1] = (short)f2bf(a0.y);
    t[2] = (short)f2bf(a0.z); t[3] = (short)f2bf(a0.w);
    t[4] = (short)f2bf(a1.x); t[5] = (short)f2bf(a1.y);
    t[6] = (short)f2bf(a1.z); t[7] = (short)f2bf(a1.w);
    af[kc] = t;
    sf[kc] = *(const short8*)(Bp + (((size_t)16 * 4 + kc) * 64 + lane) * 8);
  }
  floatx4 acc[17];
#pragma unroll
  for (int nt = 0; nt < 17; nt++) acc[nt] = (floatx4){0.f, 0.f, 0.f, 0.f};
#pragma unroll
  for (int kc = 0; kc < NKC; kc++){
#pragma unroll
    for (int nt = 0; nt < 16; nt++){
      short8 bfv = *(const short8*)(&Bs[((nt * NKC + kc) * 64 + lane) * 8]);
      acc[nt] = __builtin_amdgcn_mfma_f32_16x16x32_bf16(af[kc], bfv, acc[nt], 0, 0, 0);
    }
    acc[16] = __builtin_amdgcn_mfma_f32_16x16x32_bf16(af[kc], sf[kc], acc[16], 0, 0, 0);
  }
#pragma unroll
  for (int nt = 0; nt < 16; nt++){
#pragma unroll
    for (int i = 0; i < 4; i++){
      int r = r0 + quad * 4 + i;
      if (r < M) h1f8[(size_t)r * 256 + nt * 16 + col] = f2fp8(acc[nt][i]);
    }
  }
#pragma unroll
  for (int i = 0; i < 4; i++){
    int r = r0 + quad * 4 + i;
    if (r < M){
      float v = acc[16][i];
      if (col < 4)      asrc[(size_t)r * 4 + col] = v;
      else if (col < 8) adst[(size_t)r * 4 + (col - 4)] = v;
    }
  }
}

// ---------------------------------------------------------------- GEMM2: bf16 A, 4 LDS tiles + reg score tile
__global__ __launch_bounds__(256) void k_gemm2_att(const unsigned short* __restrict__ A,
    const unsigned short* __restrict__ Bp, unsigned char* __restrict__ h2f8,
    float* __restrict__ asrc, float* __restrict__ adst, int M){
  constexpr int K = 256, NKC = 8;
  __shared__ unsigned short Bs[64 * K];
  {
    const uint4* srcp = (const uint4*)Bp;
    uint4* dstp = (uint4*)Bs;
    for (int i = threadIdx.x; i < 2048; i += 256) dstp[i] = srcp[i];
  }
  __syncthreads();
  int wave = threadIdx.x >> 6, lane = threadIdx.x & 63;
  int quad = lane >> 4, col = lane & 15;
  int r0 = (blockIdx.x * 4 + wave) * 16;
  int rowc = min(r0 + col, M - 1);
  short8 af[NKC], sf[NKC];
#pragma unroll
  for (int kc = 0; kc < NKC; kc++){
    af[kc] = *(const short8*)(A + (size_t)rowc * K + kc * 32 + quad * 8);
    sf[kc] = *(const short8*)(Bp + (((size_t)4 * 8 + kc) * 64 + lane) * 8);
  }
  floatx4 acc[5];
#pragma unroll
  for (int nt = 0; nt < 5; nt++) acc[nt] = (floatx4){0.f, 0.f, 0.f, 0.f};
#pragma unroll
  for (int kc = 0; kc < NKC; kc++){
#pragma unroll
    for (int nt = 0; nt < 4; nt++){
      short8 bfv = *(const short8*)(&Bs[((nt * NKC + kc) * 64 + lane) * 8]);
      acc[nt] = __builtin_amdgcn_mfma_f32_16x16x32_bf16(af[kc], bfv, acc[nt], 0, 0, 0);
    }
    acc[4] = __builtin_amdgcn_mfma_f32_16x16x32_bf16(af[kc], sf[kc], acc[4], 0, 0, 0);
  }
#pragma unroll
  for (int nt = 0; nt < 4; nt++){
#pragma unroll
    for (int i = 0; i < 4; i++){
      int r = r0 + quad * 4 + i;
      if (r < M) h2f8[(size_t)r * 64 + nt * 16 + col] = f2fp8(acc[nt][i]);
    }
  }
#pragma unroll
  for (int i = 0; i < 4; i++){
    int r = r0 + quad * 4 + i;
    if (r < M){
      float v = acc[4][i];
      if (col == 0)      asrc[r] = v;
      else if (col == 1) adst[r] = v;
    }
  }
}

// ---------------------------------------------------------------- GAT layer 1 (2x unrolled, self-loop hoisted)
__global__ __launch_bounds__(256) void k_gat1(
    const int* __restrict__ row_ptr, const int2* __restrict__ csr,
    const float* __restrict__ lattr,
    const float* __restrict__ a_src, const float* __restrict__ a_dst,
    const float* __restrict__ ce, const unsigned char* __restrict__ hpre,
    const float* __restrict__ bias, unsigned short* __restrict__ hout, int n){
  int node = blockIdx.x * 4 + (threadIdx.x >> 6);
  if (node >= n) return;
  int lane = threadIdx.x & 63;
  int q = lane >> 4, lsub = lane & 15, hq = lsub >> 2;
  int start = row_ptr[node], deg = row_ptr[node + 1] - start;
  float4 as4 = *(const float4*)(a_src + (size_t)node * 4);
  float4 ad4 = *(const float4*)(a_dst + (size_t)node * 4);
  float4 ce4 = *(const float4*)ce;
  float la = lattr[node];
  float asvh = hq == 0 ? as4.x : hq == 1 ? as4.y : hq == 2 ? as4.z : as4.w;
  float advh = hq == 0 ? ad4.x : hq == 1 ? ad4.y : hq == 2 ? ad4.z : ad4.w;
  float ceh  = hq == 0 ? ce4.x : hq == 1 ? ce4.y : hq == 2 ? ce4.z : ce4.w;
  float2v acc2[8];
#pragma unroll
  for (int k = 0; k < 8; k++) acc2[k] = (float2v){0.f, 0.f};
  float dn = 0.f;
  if (q == 0){                                    // self-loop handled once
    float aself = asvh + advh + la * ceh;
    aself = aself > 0.f ? aself : 0.2f * aself;
    float wself = __expf(aself);
    dn = wself;
    uint4 u = *(const uint4*)(hpre + (size_t)node * 256 + lsub * 16);
    float2v w2 = (float2v){wself, wself};
    unsigned uu[4] = {u.x, u.y, u.z, u.w};
#pragma unroll
    for (int j = 0; j < 4; j++){
      acc2[2 * j]     = w2 * __builtin_amdgcn_cvt_pk_f32_fp8((int)uu[j], false);
      acc2[2 * j + 1] = w2 * __builtin_amdgcn_cvt_pk_f32_fp8((int)uu[j], true);
    }
  }
  for (int e = q; e < deg; e += 8){               // 2 edges per iter per quarter
    bool vB = (e + 4) < deg;
    int2 seA = csr[start + e];
    int2 seB = csr[start + (vB ? e + 4 : e)];
    float aA = a_src[(size_t)seA.x * 4 + hq] + advh + __int_as_float(seA.y) * ceh;
    aA = aA > 0.f ? aA : 0.2f * aA;
    float wA = __expf(aA);
    float aB = a_src[(size_t)seB.x * 4 + hq] + advh + __int_as_float(seB.y) * ceh;
    aB = aB > 0.f ? aB : 0.2f * aB;
    float wB = vB ? __expf(aB) : 0.f;
    uint4 uA = *(const uint4*)(hpre + (size_t)seA.x * 256 + lsub * 16);
    uint4 uB = *(const uint4*)(hpre + (size_t)seB.x * 256 + lsub * 16);
    dn += wA + wB;
    float2v wA2 = (float2v){wA, wA}, wB2 = (float2v){wB, wB};
    unsigned ua[4] = {uA.x, uA.y, uA.z, uA.w};
    unsigned ub[4] = {uB.x, uB.y, uB.z, uB.w};
#pragma unroll
    for (int j = 0; j < 4; j++){
      acc2[2 * j]     += wA2 * __builtin_amdgcn_cvt_pk_f32_fp8((int)ua[j], false);
      acc2[2 * j + 1] += wA2 * __builtin_amdgcn_cvt_pk_f32_fp8((int)ua[j], true);
      acc2[2 * j]     += wB2 * __builtin_amdgcn_cvt_pk_f32_fp8((int)ub[j], false);
      acc2[2 * j + 1] += wB2 * __builtin_amdgcn_cvt_pk_f32_fp8((int)ub[j], true);
    }
  }
  dn += __shfl_xor(dn, 16, 64);
  dn += __shfl_xor(dn, 32, 64);
#pragma unroll
  for (int k = 0; k < 8; k++){
    acc2[k].x += __shfl_xor(acc2[k].x, 16, 64);
    acc2[k].x += __shfl_xor(acc2[k].x, 32, 64);
    acc2[k].y += __shfl_xor(acc2[k].y, 16, 64);
    acc2[k].y += __shfl_xor(acc2[k].y, 32, 64);
  }
  if (q == 0){
    float inv = 1.f / dn;
    float bb[16];
#pragma unroll
    for (int j = 0; j < 4; j++){
      float4 b4 = *(const float4*)(bias + lsub * 16 + j * 4);
      bb[j * 4 + 0] = b4.x; bb[j * 4 + 1] = b4.y;
      bb[j * 4 + 2] = b4.z; bb[j * 4 + 3] = b4.w;
    }
    unsigned short o[16];
#pragma unroll
    for (int k = 0; k < 16; k++){
      float av = (k & 1) ? acc2[k >> 1].y : acc2[k >> 1].x;
      float v = av * inv + bb[k];
      v = v > 0.f ? v : (__expf(v) - 1.f);
      o[k] = f2bf(v);
    }
    unsigned short* op = hout + (size_t)node * 256 + lsub * 16;
    *(uint4*)(op)     = *(uint4*)(o);
    *(uint4*)(op + 8) = *(uint4*)(o + 8);
  }
}

// ---------------------------------------------------------------- GAT layer 2 + pair projection (2x unrolled)
__global__ __launch_bounds__(256) void k_gat2(
    const int* __restrict__ row_ptr, const int2* __restrict__ csr,
    const float* __restrict__ lattr,
    const float* __restrict__ a_src, const float* __restrict__ a_dst,
    const float* __restrict__ ce, const unsigned char* __restrict__ hpre,
    const float* __restrict__ bias, const float* __restrict__ Wlin,
    float* __restrict__ s1v, float* __restrict__ s2v, int n){
  int node = blockIdx.x * 4 + (threadIdx.x >> 6);
  if (node >= n) return;
  int lane = threadIdx.x & 63;
  int slot = lane >> 3, lsub = lane & 7;
  int start = row_ptr[node], deg = row_ptr[node + 1] - start;
  float adn = a_dst[node], c = ce[4];
  float2v acc2[4];
#pragma unroll
  for (int k = 0; k < 4; k++) acc2[k] = (float2v){0.f, 0.f};
  float dn = 0.f;
  if (slot == 0){
    float aself = a_src[node] + adn + lattr[node] * c;
    aself = aself > 0.f ? aself : 0.2f * aself;
    float wself = __expf(aself);
    dn = wself;
    uint2 u = *(const uint2*)(hpre + (size_t)node * 64 + lsub * 8);
    float2v w2 = (float2v){wself, wself};
    unsigned uu[2] = {u.x, u.y};
#pragma unroll
    for (int j = 0; j < 2; j++){
      acc2[2 * j]     = w2 * __builtin_amdgcn_cvt_pk_f32_fp8((int)uu[j], false);
      acc2[2 * j + 1] = w2 * __builtin_amdgcn_cvt_pk_f32_fp8((int)uu[j], true);
    }
  }
  for (int e = slot; e < deg; e += 16){           // 2 edges per iter per slot
    bool vB = (e + 8) < deg;
    int2 seA = csr[start + e];
    int2 seB = csr[start + (vB ? e + 8 : e)];
    float aA = a_src[seA.x] + adn + __int_as_float(seA.y) * c;
    aA = aA > 0.f ? aA : 0.2f * aA;
    float wA = __expf(aA);
    float aB = a_src[seB.x] + adn + __int_as_float(seB.y) * c;
    aB = aB > 0.f ? aB : 0.2f * aB;
    float wB = vB ? __expf(aB) : 0.f;
    uint2 uA = *(const uint2*)(hpre + (size_t)seA.x * 64 + lsub * 8);
    uint2 uB = *(const uint2*)(hpre + (size_t)seB.x * 64 + lsub * 8);
    dn += wA + wB;
    float2v wA2 = (float2v){wA, wA}, wB2 = (float2v){wB, wB};
    unsigned ua[2] = {uA.x, uA.y};
    unsigned ub[2] = {uB.x, uB.y};
#pragma unroll
    for (int j = 0; j < 2; j++){
      acc2[2 * j]     += wA2 * __builtin_amdgcn_cvt_pk_f32_fp8((int)ua[j], false);
      acc2[2 * j + 1] += wA2 * __builtin_amdgcn_cvt_pk_f32_fp8((int)ua[j], true);
      acc2[2 * j]     += wB2 * __builtin_amdgcn_cvt_pk_f32_fp8((int)ub[j], false);
      acc2[2 * j + 1] += wB2 * __builtin_amdgcn_cvt_pk_f32_fp8((int)ub[j], true);
    }
  }
#pragma unroll
  for (int o = 8; o < 64; o <<= 1){
    dn += __shfl_xor(dn, o, 64);
#pragma unroll
    for (int k = 0; k < 4; k++){
      acc2[k].x += __shfl_xor(acc2[k].x, o, 64);
      acc2[k].y += __shfl_xor(acc2[k].y, o, 64);
    }
  }
  float inv = 1.f / dn;
  float t1 = 0.f, t2 = 0.f;
#pragma unroll
  for (int k = 0; k < 8; k++){
    float av = (k & 1) ? acc2[k >> 1].y : acc2[k >> 1].x;
    float v = av * inv + bias[lsub * 8 + k];
    t1 += v * Wlin[lsub * 8 + k];
    t2 += v * Wlin[64 + lsub * 8 + k];
  }
#pragma unroll
  for (int o = 1; o < 8; o <<= 1){
    t1 += __shfl_xor(t1, o, 64);
    t2 += __shfl_xor(t2, o, 64);
  }
  if (lane == 0){ s1v[node] = t1; s2v[node] = t2; }
}

// ---------------------------------------------------------------- pair head
__global__ __launch_bounds__(256) void k_pairs(const int* __restrict__ pairs,
    const float* __restrict__ s1v, const float* __restrict__ s2v,
    const float* __restrict__ blin, float* __restrict__ out, int P){
  int p = blockIdx.x * 256 + threadIdx.x;
  if (p >= P) return;
  int i = pairs[2 * p], j = pairs[2 * p + 1];
  float x = s1v[i] + s2v[j] + blin[0];
  out[p] = 1.f / (1.f + __expf(-x));
}

// ---------------------------------------------------------------- launch
extern "C" void kernel_launch(void* const* d_in, const int* in_sizes, int n_in,
                              void* d_out, int out_size, void* d_ws, size_t ws_size,
                              hipStream_t stream) {
  const float* x     = (const float*)d_in[0];
  const int*   esrc  = (const int*)  d_in[1];
  const int*   edst  = (const int*)  d_in[2];
  const float* eattr = (const float*)d_in[3];
  const int*   pairs = (const int*)  d_in[4];
  const float* W1    = (const float*)d_in[5];
  const float* We1   = (const float*)d_in[6];
  const float* as1   = (const float*)d_in[7];
  const float* ad1   = (const float*)d_in[8];
  const float* ae1   = (const float*)d_in[9];
  const float* b1    = (const float*)d_in[10];
  const float* W2    = (const float*)d_in[11];
  const float* We2   = (const float*)d_in[12];
  const float* as2   = (const float*)d_in[13];
  const float* ad2   = (const float*)d_in[14];
  const float* ae2   = (const float*)d_in[15];
  const float* b2    = (const float*)d_in[16];
  const float* Wlin  = (const float*)d_in[17];
  const float* blin  = (const float*)d_in[18];
  float* out = (float*)d_out;

  const int N = in_sizes[0] / 128;
  const int E = in_sizes[1];
  const int P = in_sizes[4] / 2;

  char* w = (char*)d_ws;
  size_t off = 0;
  auto alloc = [&](size_t bytes) -> size_t {
    size_t r = off; off = (off + bytes + 255) & ~(size_t)255; return r;
  };
  size_t o_degp   = alloc((size_t)N * 64);   // 8 banks of u64
  size_t zero_end = off;
  size_t o_rank   = alloc((size_t)E * 4);
  size_t o_rowptr = alloc((size_t)(N + 1) * 4);
  size_t o_bsum   = alloc(1024);
  size_t o_bofs   = alloc(1024);
  size_t o_lattr  = alloc((size_t)N * 4);
  size_t o_base   = alloc((size_t)N * 32);   // 8 ints per node
  size_t o_csr    = alloc((size_t)E * 8);
  size_t o_asrc1  = alloc((size_t)N * 16);
  size_t o_adst1  = alloc((size_t)N * 16);
  size_t o_asrc2  = alloc((size_t)N * 4);
  size_t o_adst2  = alloc((size_t)N * 4);
  size_t o_ce     = alloc(32);
  size_t o_s1     = alloc((size_t)N * 4);
  size_t o_s2     = alloc((size_t)N * 4);
  size_t o_W1p    = alloc((size_t)17 * 4 * 64 * 8 * 2);
  size_t o_W2p    = alloc((size_t)5 * 8 * 64 * 8 * 2);
  size_t o_h1f8   = alloc((size_t)N * 256);
  size_t o_h1b    = alloc((size_t)N * 256 * 2);
  size_t o_h2f8   = alloc((size_t)N * 64);
  (void)ws_size;

  unsigned long long* degp = (unsigned long long*)(w + o_degp);
  int*   rank   = (int*)  (w + o_rank);
  int*   rowptr = (int*)  (w + o_rowptr);
  int*   bsum   = (int*)  (w + o_bsum);
  int*   bofs   = (int*)  (w + o_bofs);
  float* lattr  = (float*)(w + o_lattr);
  int*   base   = (int*)  (w + o_base);
  int2*  csr    = (int2*) (w + o_csr);
  float* asrc1  = (float*)(w + o_asrc1);
  float* adst1  = (float*)(w + o_adst1);
  float* asrc2  = (float*)(w + o_asrc2);
  float* adst2  = (float*)(w + o_adst2);
  float* ce     = (float*)(w + o_ce);
  float* s1v    = (float*)(w + o_s1);
  float* s2v    = (float*)(w + o_s2);
  unsigned short* W1p = (unsigned short*)(w + o_W1p);
  unsigned short* W2p = (unsigned short*)(w + o_W2p);
  unsigned char*  h1f8 = (unsigned char*)(w + o_h1f8);
  unsigned short* h1b  = (unsigned short*)(w + o_h1b);
  unsigned char*  h2f8 = (unsigned char*)(w + o_h2f8);

  hipMemsetAsync(w, 0, zero_end, stream);

  int ebl = (E + 255) / 256;
  int nbl = (N + 255) / 256;
  int wbl = (N + 3) / 4;

  // CSR build (XCD-local atomic banks)
  k_count<<<ebl, 256, 0, stream>>>(edst, eattr, degp, rank, E, N);
  k_scan1<<<nbl, 256, 0, stream>>>(degp, rowptr, bsum, N);
  k_scan2<<<1, 256, 0, stream>>>(bsum, bofs, nbl);
  k_scan3<<<nbl, 256, 0, stream>>>(rowptr, bofs, degp, lattr, base, N, E);
  k_scatter<<<ebl, 256, 0, stream>>>(esrc, edst, eattr, rank, base, csr, E);

  // weight packing + edge coeffs
  k_prep<<<109, 64, 0, stream>>>(W1, as1, ad1, W2, as2, ad2,
                                 We1, ae1, We2, ae2, W1p, W2p, ce);

  // layer 1
  k_gemm1_att<<<(N + 63) / 64, 256, 0, stream>>>(x, W1p, h1f8, asrc1, adst1, N);
  k_gat1<<<wbl, 256, 0, stream>>>(rowptr, csr, lattr, asrc1, adst1, ce,
                                  h1f8, b1, h1b, N);
  // layer 2
  k_gemm2_att<<<(N + 63) / 64, 256, 0, stream>>>(h1b, W2p, h2f8, asrc2, adst2, N);
  k_gat2<<<wbl, 256, 0, stream>>>(rowptr, csr, lattr, asrc2, adst2, ce,
                                  h2f8, b2, Wlin, s1v, s2v, N);
  // pair head
  k_pairs<<<(P + 255) / 256, 256, 0, stream>>>(pairs, s1v, s2v, blin, out, P);
}

// Round 10
// 279.359 us; speedup vs baseline: 1.1613x; 1.0030x over previous
//
#include <hip/hip_runtime.h>
#include <hip/hip_fp16.h>
#include <math.h>

typedef __attribute__((ext_vector_type(8))) short short8;
typedef __attribute__((ext_vector_type(4))) float floatx4;
typedef __attribute__((ext_vector_type(2))) float float2v;

__device__ __forceinline__ unsigned short f2bf(float f){
  unsigned int x = __float_as_uint(f);
  unsigned int r = x + 0x7fff + ((x >> 16) & 1);   // RNE
  return (unsigned short)(r >> 16);
}
__device__ __forceinline__ unsigned char f2fp8(float v){
  int pk = __builtin_amdgcn_cvt_pk_fp8_f32(v, 0.f, 0, false);
  return (unsigned char)(pk & 0xff);
}
__device__ __forceinline__ float wsumf(float v){
#pragma unroll
  for (int o = 32; o; o >>= 1) v += __shfl_xor(v, o, 64);
  return v;
}

// ---------------------------------------------------------------- count: 8 XCD-local banks (bank = blockIdx&7)
__global__ __launch_bounds__(256) void k_count(const int* __restrict__ dst,
    const float* __restrict__ eattr, unsigned long long* __restrict__ degp,
    int* __restrict__ rank, int E, int N){
  int e = blockIdx.x * 256 + threadIdx.x;
  if (e >= E) return;
  int b = blockIdx.x & 7;
  int d = dst[e];
  unsigned long long add = (1ull << 40) |
      (unsigned long long)(eattr[e] * 16777216.0f);
  unsigned long long old = atomicAdd(&degp[(size_t)b * N + d], add);
  rank[e] = (int)(old >> 40);
}

// ---------------------------------------------------------------- scans
__global__ __launch_bounds__(256) void k_scan1(const unsigned long long* __restrict__ degp,
    int* __restrict__ row_ptr, int* __restrict__ bsum, int n){
  __shared__ int sm[2][256];
  int tid = threadIdx.x, gid = blockIdx.x * 256 + tid;
  int v = 0;
  if (gid < n){
#pragma unroll
    for (int b = 0; b < 8; b++) v += (int)(degp[(size_t)b * n + gid] >> 40);
  }
  sm[0][tid] = v; __syncthreads();
  int pin = 0;
  for (int off = 1; off < 256; off <<= 1){
    int t = sm[pin][tid];
    if (tid >= off) t += sm[pin][tid - off];
    sm[pin ^ 1][tid] = t; pin ^= 1; __syncthreads();
  }
  int incl = sm[pin][tid];
  if (gid < n) row_ptr[gid] = incl - v;
  if (tid == 255) bsum[blockIdx.x] = incl;
}

__global__ __launch_bounds__(256) void k_scan2(const int* __restrict__ bsum,
    int* __restrict__ bofs, int nb){
  __shared__ int sm[2][256];
  int tid = threadIdx.x;
  int v = (tid < nb) ? bsum[tid] : 0;
  sm[0][tid] = v; __syncthreads();
  int pin = 0;
  for (int off = 1; off < 256; off <<= 1){
    int t = sm[pin][tid];
    if (tid >= off) t += sm[pin][tid - off];
    sm[pin ^ 1][tid] = t; pin ^= 1; __syncthreads();
  }
  bofs[tid] = sm[pin][tid] - v;
}

__global__ __launch_bounds__(256) void k_scan3(int* __restrict__ row_ptr,
    const int* __restrict__ bofs, const unsigned long long* __restrict__ degp,
    float* __restrict__ lattr, int* __restrict__ base, int n, int E){
  int gid = blockIdx.x * 256 + threadIdx.x;
  if (gid >= n) return;
  int rp = row_ptr[gid] + bofs[gid >> 8];
  row_ptr[gid] = rp;
  const unsigned long long M40 = (1ull << 40) - 1;
  int cum = 0; float s = 0.f;
  int bb[8];
#pragma unroll
  for (int b = 0; b < 8; b++){
    unsigned long long p = degp[(size_t)b * n + gid];
    bb[b] = rp + cum;
    cum += (int)(p >> 40);
    s += (float)(p & M40);
  }
  lattr[gid] = (s * (1.0f / 16777216.0f)) / fmaxf((float)cum, 1.0f);
  int4* bp = (int4*)(base + (size_t)gid * 8);
  bp[0] = make_int4(bb[0], bb[1], bb[2], bb[3]);
  bp[1] = make_int4(bb[4], bb[5], bb[6], bb[7]);
  if (gid == 0) row_ptr[n] = E;
}

// ---------------------------------------------------------------- scatter: CSR-ordered {src, ea}
__global__ __launch_bounds__(256) void k_scatter(const int* __restrict__ src,
    const int* __restrict__ dst, const float* __restrict__ eattr,
    const int* __restrict__ rank, const int* __restrict__ base,
    int2* __restrict__ csr, int E){
  int e = blockIdx.x * 256 + threadIdx.x;
  if (e >= E) return;
  int b = blockIdx.x & 7;
  int d = dst[e];
  int pos = base[(size_t)d * 8 + b] + rank[e];
  csr[pos] = make_int2(src[e], __float_as_int(eattr[e]));
}

// ---------------------------------------------------------------- prep: B1 tiles (17), w2v (256x4), ce + c1/c2
// w2v[k] = {W2[k]·as2, W2[k]·ad2, W2[k]·Wlin[:64], W2[k]·Wlin[64:]}
__global__ void k_prep(const float* __restrict__ W1, const float* __restrict__ as1,
    const float* __restrict__ ad1, const float* __restrict__ W2,
    const float* __restrict__ as2, const float* __restrict__ ad2,
    const float* __restrict__ We1, const float* __restrict__ ae1,
    const float* __restrict__ We2, const float* __restrict__ ae2,
    const float* __restrict__ b2, const float* __restrict__ Wlin,
    unsigned short* __restrict__ W1p, float4* __restrict__ w2v,
    float* __restrict__ ce){
  int b = blockIdx.x, lane = threadIdx.x;
  if (b < 68){
    int nt = b >> 2, kc = b & 3;
    int col = lane & 15, krow = kc * 32 + (lane >> 4) * 8;
    unsigned short tmp[8];
    if (nt < 16){
#pragma unroll
      for (int j = 0; j < 8; j++) tmp[j] = f2bf(W1[(size_t)(krow + j) * 256 + nt * 16 + col]);
    } else {
#pragma unroll
      for (int j = 0; j < 8; j++){
        float v = 0.f;
        if (col < 8){
          const float* av = (col < 4) ? as1 : ad1;
          int h = col & 3;
          for (int c = 0; c < 64; c++)
            v += W1[(size_t)(krow + j) * 256 + h * 64 + c] * av[h * 64 + c];
        }
        tmp[j] = f2bf(v);
      }
    }
    unsigned short* dstp = W1p + (((size_t)nt * 4 + kc) * 64 + lane) * 8;
    *(ushort4*)(dstp)     = make_ushort4(tmp[0], tmp[1], tmp[2], tmp[3]);
    *(ushort4*)(dstp + 4) = make_ushort4(tmp[4], tmp[5], tmp[6], tmp[7]);
  } else if (b < 72){
    int k = (b - 68) * 64 + lane;
    float4 a = make_float4(0.f, 0.f, 0.f, 0.f);
    for (int c = 0; c < 64; c++){
      float wv = W2[(size_t)k * 64 + c];
      a.x += wv * as2[c];
      a.y += wv * ad2[c];
      a.z += wv * Wlin[c];
      a.w += wv * Wlin[64 + c];
    }
    w2v[k] = a;
  } else {
    float p0 = We1[lane]       * ae1[lane];
    float p1 = We1[64 + lane]  * ae1[64 + lane];
    float p2 = We1[128 + lane] * ae1[128 + lane];
    float p3 = We1[192 + lane] * ae1[192 + lane];
    float p4 = We2[lane]       * ae2[lane];
    float c1 = b2[lane] * Wlin[lane];
    float c2 = b2[lane] * Wlin[64 + lane];
    p0 = wsumf(p0); p1 = wsumf(p1); p2 = wsumf(p2); p3 = wsumf(p3); p4 = wsumf(p4);
    c1 = wsumf(c1); c2 = wsumf(c2);
    if (lane == 0){
      ce[0] = p0; ce[1] = p1; ce[2] = p2; ce[3] = p3; ce[4] = p4;
      ce[5] = c1; ce[6] = c2;
    }
  }
}

// ---------------------------------------------------------------- GEMM1: fp32 A, 16 LDS tiles + reg score tile
__global__ __launch_bounds__(256) void k_gemm1_att(const float* __restrict__ A,
    const unsigned short* __restrict__ Bp, unsigned char* __restrict__ h1f8,
    float* __restrict__ asrc, float* __restrict__ adst, int M){
  constexpr int K = 128, NKC = 4;
  __shared__ unsigned short Bs[256 * K];
  {
    const uint4* srcp = (const uint4*)Bp;
    uint4* dstp = (uint4*)Bs;
    for (int i = threadIdx.x; i < 4096; i += 256) dstp[i] = srcp[i];
  }
  __syncthreads();
  int wave = threadIdx.x >> 6, lane = threadIdx.x & 63;
  int quad = lane >> 4, col = lane & 15;
  int r0 = (blockIdx.x * 4 + wave) * 16;
  int rowc = min(r0 + col, M - 1);
  short8 af[NKC], sf[NKC];
#pragma unroll
  for (int kc = 0; kc < NKC; kc++){
    float4 a0 = *(const float4*)(A + (size_t)rowc * K + kc * 32 + quad * 8);
    float4 a1 = *(const float4*)(A + (size_t)rowc * K + kc * 32 + quad * 8 + 4);
    short8 t;
    t[0] = (short)f2bf(a0.x); t[1] = (short)f2bf(a0.y);
    t[2] = (short)f2bf(a0.z); t[3] = (short)f2bf(a0.w);
    t[4] = (short)f2bf(a1.x); t[5] = (short)f2bf(a1.y);
    t[6] = (short)f2bf(a1.z); t[7] = (short)f2bf(a1.w);
    af[kc] = t;
    sf[kc] = *(const short8*)(Bp + (((size_t)16 * 4 + kc) * 64 + lane) * 8);
  }
  floatx4 acc[17];
#pragma unroll
  for (int nt = 0; nt < 17; nt++) acc[nt] = (floatx4){0.f, 0.f, 0.f, 0.f};
#pragma unroll
  for (int kc = 0; kc < NKC; kc++){
#pragma unroll
    for (int nt = 0; nt < 16; nt++){
      short8 bfv = *(const short8*)(&Bs[((nt * NKC + kc) * 64 + lane) * 8]);
      acc[nt] = __builtin_amdgcn_mfma_f32_16x16x32_bf16(af[kc], bfv, acc[nt], 0, 0, 0);
    }
    acc[16] = __builtin_amdgcn_mfma_f32_16x16x32_bf16(af[kc], sf[kc], acc[16], 0, 0, 0);
  }
#pragma unroll
  for (int nt = 0; nt < 16; nt++){
#pragma unroll
    for (int i = 0; i < 4; i++){
      int r = r0 + quad * 4 + i;
      if (r < M) h1f8[(size_t)r * 256 + nt * 16 + col] = f2fp8(acc[nt][i]);
    }
  }
#pragma unroll
  for (int i = 0; i < 4; i++){
    int r = r0 + quad * 4 + i;
    if (r < M){
      float v = acc[16][i];
      if (col < 4)      asrc[(size_t)r * 4 + col] = v;
      else if (col < 8) adst[(size_t)r * 4 + (col - 4)] = v;
    }
  }
}

// ---------------------------------------------------------------- GAT layer 1 (fused layer-2 projection epilogue)
// Output per node: upd = {h1·(W2@as2), h1·(W2@ad2), h1·(W2@Wlin1), h1·(W2@Wlin2)} — no h1 table written.
__global__ __launch_bounds__(256) void k_gat1(
    const int* __restrict__ row_ptr, const int2* __restrict__ csr,
    const float* __restrict__ lattr,
    const float* __restrict__ a_src, const float* __restrict__ a_dst,
    const float* __restrict__ ce, const unsigned char* __restrict__ hpre,
    const float* __restrict__ bias, const float4* __restrict__ w2v,
    float4* __restrict__ upd, int n){
  int node = blockIdx.x * 4 + (threadIdx.x >> 6);
  if (node >= n) return;
  int lane = threadIdx.x & 63;
  int q = lane >> 4, lsub = lane & 15, hq = lsub >> 2;
  int start = row_ptr[node], deg = row_ptr[node + 1] - start;
  float4 as4 = *(const float4*)(a_src + (size_t)node * 4);
  float4 ad4 = *(const float4*)(a_dst + (size_t)node * 4);
  float4 ce4 = *(const float4*)ce;
  float la = lattr[node];
  float asvh = hq == 0 ? as4.x : hq == 1 ? as4.y : hq == 2 ? as4.z : as4.w;
  float advh = hq == 0 ? ad4.x : hq == 1 ? ad4.y : hq == 2 ? ad4.z : ad4.w;
  float ceh  = hq == 0 ? ce4.x : hq == 1 ? ce4.y : hq == 2 ? ce4.z : ce4.w;
  float2v acc2[8];
#pragma unroll
  for (int k = 0; k < 8; k++) acc2[k] = (float2v){0.f, 0.f};
  float dn = 0.f;
  if (q == 0){                                    // self-loop handled once
    float aself = asvh + advh + la * ceh;
    aself = aself > 0.f ? aself : 0.2f * aself;
    float wself = __expf(aself);
    dn = wself;
    uint4 u = *(const uint4*)(hpre + (size_t)node * 256 + lsub * 16);
    float2v w2 = (float2v){wself, wself};
    unsigned uu[4] = {u.x, u.y, u.z, u.w};
#pragma unroll
    for (int j = 0; j < 4; j++){
      acc2[2 * j]     = w2 * __builtin_amdgcn_cvt_pk_f32_fp8((int)uu[j], false);
      acc2[2 * j + 1] = w2 * __builtin_amdgcn_cvt_pk_f32_fp8((int)uu[j], true);
    }
  }
  for (int e = q; e < deg; e += 8){               // 2 edges per iter per quarter
    bool vB = (e + 4) < deg;
    int2 seA = csr[start + e];
    int2 seB = csr[start + (vB ? e + 4 : e)];
    float aA = a_src[(size_t)seA.x * 4 + hq] + advh + __int_as_float(seA.y) * ceh;
    aA = aA > 0.f ? aA : 0.2f * aA;
    float wA = __expf(aA);
    float aB = a_src[(size_t)seB.x * 4 + hq] + advh + __int_as_float(seB.y) * ceh;
    aB = aB > 0.f ? aB : 0.2f * aB;
    float wB = vB ? __expf(aB) : 0.f;
    uint4 uA = *(const uint4*)(hpre + (size_t)seA.x * 256 + lsub * 16);
    uint4 uB = *(const uint4*)(hpre + (size_t)seB.x * 256 + lsub * 16);
    dn += wA + wB;
    float2v wA2 = (float2v){wA, wA}, wB2 = (float2v){wB, wB};
    unsigned ua[4] = {uA.x, uA.y, uA.z, uA.w};
    unsigned ub[4] = {uB.x, uB.y, uB.z, uB.w};
#pragma unroll
    for (int j = 0; j < 4; j++){
      acc2[2 * j]     += wA2 * __builtin_amdgcn_cvt_pk_f32_fp8((int)ua[j], false);
      acc2[2 * j + 1] += wA2 * __builtin_amdgcn_cvt_pk_f32_fp8((int)ua[j], true);
      acc2[2 * j]     += wB2 * __builtin_amdgcn_cvt_pk_f32_fp8((int)ub[j], false);
      acc2[2 * j + 1] += wB2 * __builtin_amdgcn_cvt_pk_f32_fp8((int)ub[j], true);
    }
  }
  dn += __shfl_xor(dn, 16, 64);
  dn += __shfl_xor(dn, 32, 64);
#pragma unroll
  for (int k = 0; k < 8; k++){
    acc2[k].x += __shfl_xor(acc2[k].x, 16, 64);
    acc2[k].x += __shfl_xor(acc2[k].x, 32, 64);
    acc2[k].y += __shfl_xor(acc2[k].y, 16, 64);
    acc2[k].y += __shfl_xor(acc2[k].y, 32, 64);
  }
  if (q == 0){
    float inv = 1.f / dn;
    float bb[16];
#pragma unroll
    for (int j = 0; j < 4; j++){
      float4 b4 = *(const float4*)(bias + lsub * 16 + j * 4);
      bb[j * 4 + 0] = b4.x; bb[j * 4 + 1] = b4.y;
      bb[j * 4 + 2] = b4.z; bb[j * 4 + 3] = b4.w;
    }
    float d0 = 0.f, d1 = 0.f, d2 = 0.f, d3 = 0.f;
#pragma unroll
    for (int k = 0; k < 16; k++){
      float av = (k & 1) ? acc2[k >> 1].y : acc2[k >> 1].x;
      float v = av * inv + bb[k];
      v = v > 0.f ? v : (__expf(v) - 1.f);      // elu(h1)
      float4 wv = w2v[lsub * 16 + k];
      d0 += v * wv.x; d1 += v * wv.y; d2 += v * wv.z; d3 += v * wv.w;
    }
#pragma unroll
    for (int o = 1; o < 16; o <<= 1){
      d0 += __shfl_xor(d0, o, 64);
      d1 += __shfl_xor(d1, o, 64);
      d2 += __shfl_xor(d2, o, 64);
      d3 += __shfl_xor(d3, o, 64);
    }
    if (lsub == 0) upd[node] = make_float4(d0, d1, d2, d3);
  }
}

// ---------------------------------------------------------------- GAT layer 2: scalar-only (8 lanes per node)
__global__ __launch_bounds__(256) void k_gat2(
    const int* __restrict__ row_ptr, const int2* __restrict__ csr,
    const float* __restrict__ lattr, const float4* __restrict__ upd,
    const float* __restrict__ ce,
    float* __restrict__ s1v, float* __restrict__ s2v, int n){
  int node = blockIdx.x * 32 + (threadIdx.x >> 3);
  if (node >= n) return;
  int lane8 = threadIdx.x & 7;
  int start = row_ptr[node], deg = row_ptr[node + 1] - start;
  float4 own = upd[node];
  float ad = own.y, c = ce[4];
  float t1 = 0.f, t2 = 0.f, dn = 0.f;
  if (lane8 == 0){
    float a = own.x + ad + lattr[node] * c;
    a = a > 0.f ? a : 0.2f * a;
    float w = __expf(a);
    dn = w; t1 = w * own.z; t2 = w * own.w;
  }
  for (int e = lane8; e < deg; e += 8){
    int2 se = csr[start + e];
    float4 o = upd[se.x];
    float a = o.x + ad + __int_as_float(se.y) * c;
    a = a > 0.f ? a : 0.2f * a;
    float w = __expf(a);
    dn += w; t1 += w * o.z; t2 += w * o.w;
  }
#pragma unroll
  for (int o = 1; o < 8; o <<= 1){
    dn += __shfl_xor(dn, o, 64);
    t1 += __shfl_xor(t1, o, 64);
    t2 += __shfl_xor(t2, o, 64);
  }
  if (lane8 == 0){
    float inv = 1.f / dn;
    s1v[node] = t1 * inv + ce[5];
    s2v[node] = t2 * inv + ce[6];
  }
}

// ---------------------------------------------------------------- pair head
__global__ __launch_bounds__(256) void k_pairs(const int* __restrict__ pairs,
    const float* __restrict__ s1v, const float* __restrict__ s2v,
    const float* __restrict__ blin, float* __restrict__ out, int P){
  int p = blockIdx.x * 256 + threadIdx.x;
  if (p >= P) return;
  int i = pairs[2 * p], j = pairs[2 * p + 1];
  float x = s1v[i] + s2v[j] + blin[0];
  out[p] = 1.f / (1.f + __expf(-x));
}

// ---------------------------------------------------------------- launch
extern "C" void kernel_launch(void* const* d_in, const int* in_sizes, int n_in,
                              void* d_out, int out_size, void* d_ws, size_t ws_size,
                              hipStream_t stream) {
  const float* x     = (const float*)d_in[0];
  const int*   esrc  = (const int*)  d_in[1];
  const int*   edst  = (const int*)  d_in[2];
  const float* eattr = (const float*)d_in[3];
  const int*   pairs = (const int*)  d_in[4];
  const float* W1    = (const float*)d_in[5];
  const float* We1   = (const float*)d_in[6];
  const float* as1   = (const float*)d_in[7];
  const float* ad1   = (const float*)d_in[8];
  const float* ae1   = (const float*)d_in[9];
  const float* b1    = (const float*)d_in[10];
  const float* W2    = (const float*)d_in[11];
  const float* We2   = (const float*)d_in[12];
  const float* as2   = (const float*)d_in[13];
  const float* ad2   = (const float*)d_in[14];
  const float* ae2   = (const float*)d_in[15];
  const float* b2    = (const float*)d_in[16];
  const float* Wlin  = (const float*)d_in[17];
  const float* blin  = (const float*)d_in[18];
  float* out = (float*)d_out;

  const int N = in_sizes[0] / 128;
  const int E = in_sizes[1];
  const int P = in_sizes[4] / 2;

  char* w = (char*)d_ws;
  size_t off = 0;
  auto alloc = [&](size_t bytes) -> size_t {
    size_t r = off; off = (off + bytes + 255) & ~(size_t)255; return r;
  };
  size_t o_degp   = alloc((size_t)N * 64);   // 8 banks of u64
  size_t zero_end = off;
  size_t o_rank   = alloc((size_t)E * 4);
  size_t o_rowptr = alloc((size_t)(N + 1) * 4);
  size_t o_bsum   = alloc(1024);
  size_t o_bofs   = alloc(1024);
  size_t o_lattr  = alloc((size_t)N * 4);
  size_t o_base   = alloc((size_t)N * 32);
  size_t o_csr    = alloc((size_t)E * 8);
  size_t o_asrc1  = alloc((size_t)N * 16);
  size_t o_adst1  = alloc((size_t)N * 16);
  size_t o_upd    = alloc((size_t)N * 16);
  size_t o_ce     = alloc(64);
  size_t o_s1     = alloc((size_t)N * 4);
  size_t o_s2     = alloc((size_t)N * 4);
  size_t o_W1p    = alloc((size_t)17 * 4 * 64 * 8 * 2);
  size_t o_w2v    = alloc(256 * 16);
  size_t o_h1f8   = alloc((size_t)N * 256);
  (void)ws_size;

  unsigned long long* degp = (unsigned long long*)(w + o_degp);
  int*   rank   = (int*)  (w + o_rank);
  int*   rowptr = (int*)  (w + o_rowptr);
  int*   bsum   = (int*)  (w + o_bsum);
  int*   bofs   = (int*)  (w + o_bofs);
  float* lattr  = (float*)(w + o_lattr);
  int*   base   = (int*)  (w + o_base);
  int2*  csr    = (int2*) (w + o_csr);
  float* asrc1  = (float*)(w + o_asrc1);
  float* adst1  = (float*)(w + o_adst1);
  float4* upd   = (float4*)(w + o_upd);
  float* ce     = (float*)(w + o_ce);
  float* s1v    = (float*)(w + o_s1);
  float* s2v    = (float*)(w + o_s2);
  unsigned short* W1p = (unsigned short*)(w + o_W1p);
  float4* w2v   = (float4*)(w + o_w2v);
  unsigned char* h1f8 = (unsigned char*)(w + o_h1f8);

  hipMemsetAsync(w, 0, zero_end, stream);

  int ebl = (E + 255) / 256;
  int nbl = (N + 255) / 256;
  int wbl = (N + 3) / 4;

  // CSR build (XCD-local atomic banks)
  k_count<<<ebl, 256, 0, stream>>>(edst, eattr, degp, rank, E, N);
  k_scan1<<<nbl, 256, 0, stream>>>(degp, rowptr, bsum, N);
  k_scan2<<<1, 256, 0, stream>>>(bsum, bofs, nbl);
  k_scan3<<<nbl, 256, 0, stream>>>(rowptr, bofs, degp, lattr, base, N, E);
  k_scatter<<<ebl, 256, 0, stream>>>(esrc, edst, eattr, rank, base, csr, E);

  // weight packing + precontracted layer-2 vectors + edge coeffs
  k_prep<<<73, 64, 0, stream>>>(W1, as1, ad1, W2, as2, ad2,
                                We1, ae1, We2, ae2, b2, Wlin, W1p, w2v, ce);

  // layer 1 (GEMM + scores)
  k_gemm1_att<<<(N + 63) / 64, 256, 0, stream>>>(x, W1p, h1f8, asrc1, adst1, N);
  // layer-1 aggregation + fused layer-2 projection
  k_gat1<<<wbl, 256, 0, stream>>>(rowptr, csr, lattr, asrc1, adst1, ce,
                                  h1f8, b1, w2v, upd, N);
  // layer-2 aggregation (scalar only)
  k_gat2<<<(N + 31) / 32, 256, 0, stream>>>(rowptr, csr, lattr, upd, ce,
                                            s1v, s2v, N);
  // pair head
  k_pairs<<<(P + 255) / 256, 256, 0, stream>>>(pairs, s1v, s2v, blin, out, P);
}